// Round 15
// baseline (416.930 us; speedup 1.0000x reference)
//
#include <hip/hip_runtime.h>
#include <hip/hip_bf16.h>

#define DEV_INLINE __device__ __forceinline__

typedef __attribute__((ext_vector_type(8))) short short8v;
typedef __attribute__((ext_vector_type(4))) float f32x4;

DEV_INLINE float lrelu(float v) { return fmaxf(v, 0.2f * v); }

DEV_INLINE unsigned int cvt_pk_bf16(float lo, float hi) {
    unsigned int r;
    asm("v_cvt_pk_bf16_f32 %0, %1, %2" : "=v"(r) : "v"(lo), "v"(hi));
    return r;
}

DEV_INLINE unsigned short f2bf_rne(float f) {
    unsigned int b = __float_as_uint(f);
    return (unsigned short)((b + 0x7FFFu + ((b >> 16) & 1u)) >> 16);
}

DEV_INLINE unsigned int pack_bf16(float lo, float hi) {
    return (unsigned int)f2bf_rne(lo) | ((unsigned int)f2bf_rne(hi) << 16);
}

DEV_INLINE float bf_lo(unsigned int u) { return __uint_as_float(u << 16); }
DEV_INLINE float bf_hi(unsigned int u) { return __uint_as_float(u & 0xFFFF0000u); }

// ---------------------------------------------------------------------------
// Preprocess: edge-count histogram + GATConv1 projection/attention scores.
// Both independent of all other kernels; grid-stride over edges and nodes.
// ---------------------------------------------------------------------------
__global__ __launch_bounds__(256) void k_pre(const int* __restrict__ ei,
                                             int* __restrict__ counts,
                                             const float* __restrict__ x,
                                             const float* __restrict__ gW1,
                                             const float* __restrict__ as_w,
                                             const float* __restrict__ ad_w,
                                             unsigned short* __restrict__ h1b,
                                             float* __restrict__ a1s,
                                             float* __restrict__ a1d,
                                             int N, int E) {
    int tid = threadIdx.x, lane = tid & 63;
    int gid = blockIdx.x * 256 + tid;
    int stride = gridDim.x * 256;

    // edge-count histogram
    for (int e = gid; e < E; e += stride) atomicAdd(&counts[ei[E + e]], 1);

    // g1a: wave per node, grid-stride
    float wa[10], wb[10];
#pragma unroll
    for (int i = 0; i < 10; ++i) { wa[i] = gW1[i * 128 + lane]; wb[i] = gW1[i * 128 + 64 + lane]; }
    int c = lane & 31;
    int headA = lane >> 5;
    float asA = as_w[headA * 32 + c], asB = as_w[(headA + 2) * 32 + c];
    float adA = ad_w[headA * 32 + c], adB = ad_w[(headA + 2) * 32 + c];

    int wid = gid >> 6, nwav = stride >> 6;
    for (int n = wid; n < N; n += nwav) {
        const float* xp = x + (size_t)n * 10;
        float ha = 0.f, hb = 0.f;
#pragma unroll
        for (int i = 0; i < 10; ++i) { float xv = xp[i]; ha = fmaf(xv, wa[i], ha); hb = fmaf(xv, wb[i], hb); }
        float ps_a = ha * asA, ps_b = hb * asB;
        float pd_a = ha * adA, pd_b = hb * adB;
#pragma unroll
        for (int m = 1; m < 32; m <<= 1) {
            ps_a += __shfl_xor(ps_a, m); ps_b += __shfl_xor(ps_b, m);
            pd_a += __shfl_xor(pd_a, m); pd_b += __shfl_xor(pd_b, m);
        }
        h1b[(size_t)n * 128 + lane]      = f2bf_rne(ha);
        h1b[(size_t)n * 128 + 64 + lane] = f2bf_rne(hb);
        if (c == 0) {
            a1s[n * 4 + headA]     = ps_a;
            a1s[n * 4 + 2 + headA] = ps_b;
            a1d[n * 4 + headA]     = pd_a;
            a1d[n * 4 + 2 + headA] = pd_b;
        }
    }
}

// ---------------------------------------------------------------------------
// CSR scan kernels
// ---------------------------------------------------------------------------
__global__ __launch_bounds__(1024) void k_scan1(const int* __restrict__ counts,
                                                int* __restrict__ rowptr,
                                                int* __restrict__ partials, int N) {
    __shared__ int sd[1024];
    int li = threadIdx.x;
    int i  = blockIdx.x * 1024 + li;
    int v  = (i < N) ? counts[i] : 0;
    sd[li] = v;
    __syncthreads();
    for (int off = 1; off < 1024; off <<= 1) {
        int t = (li >= off) ? sd[li - off] : 0;
        __syncthreads();
        sd[li] += t;
        __syncthreads();
    }
    int inc = sd[li];
    if (i < N) rowptr[i + 1] = inc;
    if (li == 1023) partials[blockIdx.x] = inc;   // raw chunk totals
}

__global__ void k_scan3(int* __restrict__ rowptr, const int* __restrict__ partials,
                        int* __restrict__ nxt, int N) {
    int i = blockIdx.x * blockDim.x + threadIdx.x;
    if (i > N) return;
    int v;
    if (i == 0) { v = 0; rowptr[0] = 0; }
    else {
        int blk = (i - 1) >> 10;
        int pp = 0;
        for (int b = 0; b < blk; ++b) pp += partials[b];
        v = rowptr[i] + pp;
        rowptr[i] = v;
    }
    if (i < N) nxt[i] = v;
}

#define SC_K 8
#define SC_P 16
__global__ __launch_bounds__(256) void k_scatter(const int* __restrict__ ei,
                                                 int* __restrict__ nxt,
                                                 int* __restrict__ col,
                                                 int E, int range) {
    int t = threadIdx.x;
    int base = blockIdx.x * (256 * SC_K);
    int s[SC_K], d[SC_K];
#pragma unroll
    for (int k = 0; k < SC_K; ++k) {
        int e = base + k * 256 + t;
        bool v = (e < E);
        s[k] = v ? ei[e] : 0;
        d[k] = v ? ei[E + e] : -1;
    }
    int lo = 0;
    for (int p = 0; p < SC_P; ++p, lo += range) {
        int hi = lo + range;
#pragma unroll
        for (int k = 0; k < SC_K; ++k) {
            if (d[k] >= lo && d[k] < hi) {
                int pos = atomicAdd(&nxt[d[k]], 1);
                col[pos] = s[k];
            }
        }
        __syncthreads();
    }
}

// ---------------------------------------------------------------------------
// Per-node temporal compute from an LDS slot (512 floats). MFMA 16x16x32.
// ---------------------------------------------------------------------------
DEV_INLINE void temporal_node(const float* wb, int col, int g, const short8v* B,
                              int lane, unsigned short* mb, size_t n) {
    float sum0 = 0.f, sum1 = 0.f, sum2 = 0.f, sum3 = 0.f;
#pragma unroll
    for (int tt = 0; tt < 4; ++tt) {
        int t = tt * 16 + col;
        bool valid = (t < 50);
        float x0 = 0.f, x1 = 0.f, x2 = 0.f, x3 = 0.f;
        float x4 = 0.f, x5 = 0.f, x6 = 0.f, x7 = 0.f;
        const float* rp = wb + t * 10;
        if (g == 0 && valid) {
            float2 p0 = *reinterpret_cast<const float2*>(rp);
            float2 p1 = *reinterpret_cast<const float2*>(rp + 2);
            float2 p2 = *reinterpret_cast<const float2*>(rp + 4);
            float2 p3 = *reinterpret_cast<const float2*>(rp + 6);
            x0 = p0.x; x1 = p0.y; x2 = p1.x; x3 = p1.y;
            x4 = p2.x; x5 = p2.y; x6 = p3.x; x7 = p3.y;
        } else if (g == 1 && valid) {
            float2 p4 = *reinterpret_cast<const float2*>(rp + 8);
            x0 = p4.x; x1 = p4.y; x2 = 1.0f;
        }
        union { short8v v; unsigned int w[4]; } au;
        au.w[0] = cvt_pk_bf16(x0, x1);
        au.w[1] = cvt_pk_bf16(x2, x3);
        au.w[2] = cvt_pk_bf16(x4, x5);
        au.w[3] = cvt_pk_bf16(x6, x7);

        f32x4 z = {0.f, 0.f, 0.f, 0.f};
        f32x4 c0 = __builtin_amdgcn_mfma_f32_16x16x32_bf16(au.v, B[0], z, 0, 0, 0);
        f32x4 c1 = __builtin_amdgcn_mfma_f32_16x16x32_bf16(au.v, B[1], z, 0, 0, 0);
        f32x4 c2 = __builtin_amdgcn_mfma_f32_16x16x32_bf16(au.v, B[2], z, 0, 0, 0);
        f32x4 c3 = __builtin_amdgcn_mfma_f32_16x16x32_bf16(au.v, B[3], z, 0, 0, 0);
#pragma unroll
        for (int i = 0; i < 4; ++i) {
            sum0 += fmaxf(c0[i], 0.f);
            sum1 += fmaxf(c1[i], 0.f);
            sum2 += fmaxf(c2[i], 0.f);
            sum3 += fmaxf(c3[i], 0.f);
        }
    }
    sum0 += __shfl_xor(sum0, 16); sum0 += __shfl_xor(sum0, 32);
    sum1 += __shfl_xor(sum1, 16); sum1 += __shfl_xor(sum1, 32);
    sum2 += __shfl_xor(sum2, 16); sum2 += __shfl_xor(sum2, 32);
    sum3 += __shfl_xor(sum3, 16); sum3 += __shfl_xor(sum3, 32);
    float mv = (g == 0) ? sum0 : (g == 1) ? sum1 : (g == 2) ? sum2 : sum3;
    mb[n * 64 + lane] = f2bf_rne(mv * 0.02f);
}

// ---------------------------------------------------------------------------
// Temporal encoder (+ folded classifier-weight fuse). Static double buffer,
// 2-node unrolled loop, distance-2 register staging. (Count histogram moved
// to k_pre for profiler visibility of the temporal core.)
// ---------------------------------------------------------------------------
__global__ __launch_bounds__(256) void k_temporal(const float* __restrict__ td,
                                                  const float* __restrict__ tW1,
                                                  const float* __restrict__ tb1,
                                                  const float* __restrict__ tW2,
                                                  const float* __restrict__ cW1,
                                                  const float* __restrict__ tb2,
                                                  const float* __restrict__ cb1,
                                                  unsigned short* __restrict__ Wf,
                                                  float* __restrict__ bcf,
                                                  unsigned short* __restrict__ mb,
                                                  int N) {
    __shared__ float b0lds[4][512];
    __shared__ float b1lds[4][512];
    int tid = threadIdx.x, lane = tid & 63, wv = tid >> 6;
    int gid = blockIdx.x * 256 + tid;

    // ---- folded k_fuse ----
    if (gid < 4096) {
        int i = gid >> 6, c = gid & 63;
        float s = 0.f;
#pragma unroll 8
        for (int k = 0; k < 64; ++k) s = fmaf(tW2[i * 64 + k], cW1[k * 64 + c], s);
        Wf[gid] = f2bf_rne(s);
    } else if (gid < 8192) {
        Wf[gid] = f2bf_rne(cW1[gid]);
    } else if (gid < 8256) {
        int c = gid - 8192;
        float s = cb1[c];
#pragma unroll 8
        for (int k = 0; k < 64; ++k) s = fmaf(tb2[k], cW1[k * 64 + c], s);
        bcf[c] = s;
    }

    int wid  = gid >> 6;
    int nwav = (gridDim.x * 256) >> 6;
    int col  = lane & 15;
    int g    = lane >> 4;

    int chunk = (N + nwav - 1) / nwav;
    int n0 = wid * chunk;
    int n1 = min(n0 + chunk, N);
    if (n0 >= n1) return;
    int cnt = n1 - n0;

    // B-frags (bias folded at k=10)
    short8v B[4];
#pragma unroll
    for (int cb = 0; cb < 4; ++cb) {
        union { short8v v; unsigned short u[8]; } bu;
#pragma unroll
        for (int j = 0; j < 8; ++j) {
            int f = g * 8 + j;
            int c = cb * 16 + col;
            float w = (f < 10) ? tW1[f * 64 + c] : ((f == 10) ? tb1[c] : 0.f);
            bu.u[j] = f2bf_rne(w);
        }
        B[cb] = bu.v;
    }

    float* buf0 = &b0lds[wv][0];
    float* buf1 = &b1lds[wv][0];
    float4 zero4 = make_float4(0.f, 0.f, 0.f, 0.f);

#define LOADROW(J, A, Bv)                                                      \
    {                                                                          \
        int nn = n0 + (J); if (nn > n1 - 1) nn = n1 - 1;                       \
        const float4* rr = reinterpret_cast<const float4*>(td + (size_t)nn * 500); \
        A = rr[lane];                                                          \
        Bv = (lane < 61) ? rr[64 + lane] : zero4;                              \
    }
#define WRITEBUF(BUF, A, Bv)                                                   \
    {                                                                          \
        *reinterpret_cast<float4*>((BUF) + 4 * lane) = A;                      \
        if (lane < 61) *reinterpret_cast<float4*>((BUF) + 256 + 4 * lane) = Bv;\
    }

    float4 aA, bA, aB, bB;
    LOADROW(0, aA, bA)
    LOADROW(1, aB, bB)
    WRITEBUF(buf0, aA, bA)
    LOADROW(2, aA, bA)
    WRITEBUF(buf1, aB, bB)
    LOADROW(3, aB, bB)

    int i = 0;
    for (; i + 1 < cnt; i += 2) {
        temporal_node(buf0, col, g, B, lane, mb, (size_t)(n0 + i));
        WRITEBUF(buf0, aA, bA)
        LOADROW(i + 4, aA, bA)
        temporal_node(buf1, col, g, B, lane, mb, (size_t)(n0 + i + 1));
        WRITEBUF(buf1, aB, bB)
        LOADROW(i + 5, aB, bB)
    }
    if (i < cnt)
        temporal_node(buf0, col, g, B, lane, mb, (size_t)(n0 + i));
#undef LOADROW
#undef WRITEBUF
}

// ---------------------------------------------------------------------------
// GATConv1 aggregation. Quarter-wave per edge stream (4 streams x 16 lanes);
// lane owns 8 channels via uint4. Serial chain ~deg/4; combine shfl_xor(16,32).
// ---------------------------------------------------------------------------
__global__ __launch_bounds__(256) void k_g1b(const int* __restrict__ rowptr,
                                             const int* __restrict__ col,
                                             const unsigned int* __restrict__ h1u,
                                             const float* __restrict__ a1s,
                                             const float* __restrict__ a1d,
                                             const float* __restrict__ gb1,
                                             unsigned int* __restrict__ out1u, int N) {
    int tid = threadIdx.x, lane = tid & 63;
    int n0 = blockIdx.x * 4 + (tid >> 6);
    int n  = __builtin_amdgcn_readfirstlane(n0 < N ? n0 : N - 1);

    int start = rowptr[n], end = rowptr[n + 1];
    int q = lane >> 4, c = lane & 15;     // stream q; channels 8c..8c+7
    int hsel = c >> 2;                    // head
    float advh = a1d[n * 4 + hsel];
    const uint4* h1q = reinterpret_cast<const uint4*>(h1u);

    float den = 0.f;
    float a0 = 0.f, a1v = 0.f, a2v = 0.f, a3v = 0.f;
    float a4 = 0.f, a5 = 0.f, a6 = 0.f, a7 = 0.f;
    if (q == 0) {                         // self loop on stream 0
        float w = __expf(lrelu(a1s[n * 4 + hsel] + advh));
        uint4 u = h1q[(size_t)n * 16 + c];
        den = w;
        a0 = w * bf_lo(u.x); a1v = w * bf_hi(u.x);
        a2v = w * bf_lo(u.y); a3v = w * bf_hi(u.y);
        a4 = w * bf_lo(u.z); a5 = w * bf_hi(u.z);
        a6 = w * bf_lo(u.w); a7 = w * bf_hi(u.w);
    }
    int e = start + q;
    for (; e + 4 < end; e += 8) {         // 2-edge unroll per stream
        int s0 = col[e], s1 = col[e + 4];
        float q0 = a1s[s0 * 4 + hsel];
        float q1 = a1s[s1 * 4 + hsel];
        uint4 u0 = h1q[(size_t)s0 * 16 + c];
        uint4 u1 = h1q[(size_t)s1 * 16 + c];
        float w0 = __expf(lrelu(q0 + advh));
        float w1 = __expf(lrelu(q1 + advh));
        den += w0 + w1;
        a0 = fmaf(w0, bf_lo(u0.x), a0); a1v = fmaf(w0, bf_hi(u0.x), a1v);
        a2v = fmaf(w0, bf_lo(u0.y), a2v); a3v = fmaf(w0, bf_hi(u0.y), a3v);
        a4 = fmaf(w0, bf_lo(u0.z), a4); a5 = fmaf(w0, bf_hi(u0.z), a5);
        a6 = fmaf(w0, bf_lo(u0.w), a6); a7 = fmaf(w0, bf_hi(u0.w), a7);
        a0 = fmaf(w1, bf_lo(u1.x), a0); a1v = fmaf(w1, bf_hi(u1.x), a1v);
        a2v = fmaf(w1, bf_lo(u1.y), a2v); a3v = fmaf(w1, bf_hi(u1.y), a3v);
        a4 = fmaf(w1, bf_lo(u1.z), a4); a5 = fmaf(w1, bf_hi(u1.z), a5);
        a6 = fmaf(w1, bf_lo(u1.w), a6); a7 = fmaf(w1, bf_hi(u1.w), a7);
    }
    if (e < end) {
        int s = col[e];
        float qv = a1s[s * 4 + hsel];
        uint4 u = h1q[(size_t)s * 16 + c];
        float w = __expf(lrelu(qv + advh));
        den += w;
        a0 = fmaf(w, bf_lo(u.x), a0); a1v = fmaf(w, bf_hi(u.x), a1v);
        a2v = fmaf(w, bf_lo(u.y), a2v); a3v = fmaf(w, bf_hi(u.y), a3v);
        a4 = fmaf(w, bf_lo(u.z), a4); a5 = fmaf(w, bf_hi(u.z), a5);
        a6 = fmaf(w, bf_lo(u.w), a6); a7 = fmaf(w, bf_hi(u.w), a7);
    }
#define RED2(v) v += __shfl_xor(v, 16); v += __shfl_xor(v, 32);
    RED2(den) RED2(a0) RED2(a1v) RED2(a2v) RED2(a3v)
    RED2(a4) RED2(a5) RED2(a6) RED2(a7)
#undef RED2

    if (n0 < N && lane < 16) {
        float inv = 1.f / den;
        float v0 = a0 * inv + gb1[8 * c + 0];
        float v1 = a1v * inv + gb1[8 * c + 1];
        float v2 = a2v * inv + gb1[8 * c + 2];
        float v3 = a3v * inv + gb1[8 * c + 3];
        float v4 = a4 * inv + gb1[8 * c + 4];
        float v5 = a5 * inv + gb1[8 * c + 5];
        float v6 = a6 * inv + gb1[8 * c + 6];
        float v7 = a7 * inv + gb1[8 * c + 7];
        v0 = (v0 > 0.f) ? v0 : (__expf(v0) - 1.f);
        v1 = (v1 > 0.f) ? v1 : (__expf(v1) - 1.f);
        v2 = (v2 > 0.f) ? v2 : (__expf(v2) - 1.f);
        v3 = (v3 > 0.f) ? v3 : (__expf(v3) - 1.f);
        v4 = (v4 > 0.f) ? v4 : (__expf(v4) - 1.f);
        v5 = (v5 > 0.f) ? v5 : (__expf(v5) - 1.f);
        v6 = (v6 > 0.f) ? v6 : (__expf(v6) - 1.f);
        v7 = (v7 > 0.f) ? v7 : (__expf(v7) - 1.f);
        uint4 o;
        o.x = pack_bf16(v0, v1); o.y = pack_bf16(v2, v3);
        o.z = pack_bf16(v4, v5); o.w = pack_bf16(v6, v7);
        *reinterpret_cast<uint4*>(out1u + (size_t)n * 64 + 4 * c) = o;
    }
}

// ---------------------------------------------------------------------------
// GATConv2 projection via MFMA: h2 = out1 @ gW2 (bf16 in/out) + scores.
// ---------------------------------------------------------------------------
__global__ __launch_bounds__(256) void k_g2a(const unsigned short* __restrict__ out1b,
                                             const float* __restrict__ gW2,
                                             const float* __restrict__ a2sw,
                                             const float* __restrict__ a2dw,
                                             unsigned short* __restrict__ h2b,
                                             float* __restrict__ a2s,
                                             float* __restrict__ a2d, int N) {
    int lane = threadIdx.x & 63;
    int wid  = (blockIdx.x * blockDim.x + threadIdx.x) >> 6;
    int nwav = (gridDim.x * blockDim.x) >> 6;
    int col = lane & 15, g4 = lane >> 4;

    short8v Bf[4][4];
#pragma unroll
    for (int ks = 0; ks < 4; ++ks)
#pragma unroll
        for (int cb = 0; cb < 4; ++cb) {
            union { short8v v; unsigned short u[8]; } bu;
#pragma unroll
            for (int j = 0; j < 8; ++j)
                bu.u[j] = f2bf_rne(gW2[(ks * 32 + g4 * 8 + j) * 64 + cb * 16 + col]);
            Bf[ks][cb] = bu.v;
        }
    float asv[4], adv[4];
#pragma unroll
    for (int cb = 0; cb < 4; ++cb) { asv[cb] = a2sw[cb * 16 + col]; adv[cb] = a2dw[cb * 16 + col]; }

    int ntile = (N + 15) >> 4;
    for (int t = wid; t < ntile; t += nwav) {
        int n0 = t * 16;
        int node = n0 + col; if (node >= N) node = N - 1;
        const unsigned short* xr = out1b + (size_t)node * 128;
        f32x4 acc0 = {0.f, 0.f, 0.f, 0.f}, acc1 = acc0, acc2 = acc0, acc3 = acc0;
#pragma unroll
        for (int ks = 0; ks < 4; ++ks) {
            short8v a = *reinterpret_cast<const short8v*>(xr + ks * 32 + g4 * 8);
            acc0 = __builtin_amdgcn_mfma_f32_16x16x32_bf16(a, Bf[ks][0], acc0, 0, 0, 0);
            acc1 = __builtin_amdgcn_mfma_f32_16x16x32_bf16(a, Bf[ks][1], acc1, 0, 0, 0);
            acc2 = __builtin_amdgcn_mfma_f32_16x16x32_bf16(a, Bf[ks][2], acc2, 0, 0, 0);
            acc3 = __builtin_amdgcn_mfma_f32_16x16x32_bf16(a, Bf[ks][3], acc3, 0, 0, 0);
        }
        float ps[4] = {0.f, 0.f, 0.f, 0.f}, pd[4] = {0.f, 0.f, 0.f, 0.f};
#define G2A_EPI(CB, ACC)                                                      \
        {                                                                     \
            _Pragma("unroll")                                                 \
            for (int i = 0; i < 4; ++i) {                                     \
                float v = ACC[i];                                             \
                int r = n0 + g4 * 4 + i;                                      \
                if (r < N) h2b[(size_t)r * 64 + CB * 16 + col] = f2bf_rne(v); \
                ps[i] = fmaf(v, asv[CB], ps[i]);                              \
                pd[i] = fmaf(v, adv[CB], pd[i]);                              \
            }                                                                 \
        }
        G2A_EPI(0, acc0) G2A_EPI(1, acc1) G2A_EPI(2, acc2) G2A_EPI(3, acc3)
#undef G2A_EPI
#pragma unroll
        for (int i = 0; i < 4; ++i) {
            ps[i] += __shfl_xor(ps[i], 1); ps[i] += __shfl_xor(ps[i], 2);
            ps[i] += __shfl_xor(ps[i], 4); ps[i] += __shfl_xor(ps[i], 8);
            pd[i] += __shfl_xor(pd[i], 1); pd[i] += __shfl_xor(pd[i], 2);
            pd[i] += __shfl_xor(pd[i], 4); pd[i] += __shfl_xor(pd[i], 8);
        }
        if (col == 0) {
#pragma unroll
            for (int i = 0; i < 4; ++i) {
                int r = n0 + g4 * 4 + i;
                if (r < N) { a2s[r] = ps[i]; a2d[r] = pd[i]; }
            }
        }
    }
}

// ---------------------------------------------------------------------------
// GATConv2 aggregation. Eighth-wave per edge stream (8 streams x 8 lanes),
// 8 ch/lane via uint4. Chain ~deg/8; combine shfl_xor(8,16,32).
// ---------------------------------------------------------------------------
__global__ __launch_bounds__(256) void k_g2b(const int* __restrict__ rowptr,
                                             const int* __restrict__ col,
                                             const unsigned int* __restrict__ h2u,
                                             const float* __restrict__ a2s,
                                             const float* __restrict__ a2d,
                                             const float* __restrict__ gb2,
                                             unsigned int* __restrict__ gu, int N) {
    int tid = threadIdx.x, lane = tid & 63;
    int n0 = blockIdx.x * 4 + (tid >> 6);
    int n  = __builtin_amdgcn_readfirstlane(n0 < N ? n0 : N - 1);

    int start = rowptr[n], end = rowptr[n + 1];
    int q = lane >> 3, c = lane & 7;     // stream q; channels 8c..8c+7
    float ad = a2d[n];
    const uint4* h2q = reinterpret_cast<const uint4*>(h2u);

    float den = 0.f;
    float a0 = 0.f, a1v = 0.f, a2v = 0.f, a3v = 0.f;
    float a4 = 0.f, a5 = 0.f, a6 = 0.f, a7 = 0.f;
    if (q == 0) {                        // self loop on stream 0
        float w = __expf(lrelu(a2s[n] + ad));
        uint4 u = h2q[(size_t)n * 8 + c];
        den = w;
        a0 = w * bf_lo(u.x); a1v = w * bf_hi(u.x);
        a2v = w * bf_lo(u.y); a3v = w * bf_hi(u.y);
        a4 = w * bf_lo(u.z); a5 = w * bf_hi(u.z);
        a6 = w * bf_lo(u.w); a7 = w * bf_hi(u.w);
    }
    for (int e = start + q; e < end; e += 8) {
        int s = col[e];
        float w = __expf(lrelu(a2s[s] + ad));
        uint4 u = h2q[(size_t)s * 8 + c];
        den += w;
        a0 = fmaf(w, bf_lo(u.x), a0); a1v = fmaf(w, bf_hi(u.x), a1v);
        a2v = fmaf(w, bf_lo(u.y), a2v); a3v = fmaf(w, bf_hi(u.y), a3v);
        a4 = fmaf(w, bf_lo(u.z), a4); a5 = fmaf(w, bf_hi(u.z), a5);
        a6 = fmaf(w, bf_lo(u.w), a6); a7 = fmaf(w, bf_hi(u.w), a7);
    }
#define RED3(v) v += __shfl_xor(v, 8); v += __shfl_xor(v, 16); v += __shfl_xor(v, 32);
    RED3(den) RED3(a0) RED3(a1v) RED3(a2v) RED3(a3v)
    RED3(a4) RED3(a5) RED3(a6) RED3(a7)
#undef RED3

    if (n0 < N && lane < 8) {
        float inv = 1.f / den;
        uint4 o;
        o.x = pack_bf16(a0 * inv + gb2[8 * c + 0], a1v * inv + gb2[8 * c + 1]);
        o.y = pack_bf16(a2v * inv + gb2[8 * c + 2], a3v * inv + gb2[8 * c + 3]);
        o.z = pack_bf16(a4 * inv + gb2[8 * c + 4], a5 * inv + gb2[8 * c + 5]);
        o.w = pack_bf16(a6 * inv + gb2[8 * c + 6], a7 * inv + gb2[8 * c + 7]);
        *reinterpret_cast<uint4*>(gu + (size_t)n * 32 + 4 * c) = o;
    }
}

// ---------------------------------------------------------------------------
// Classifier via MFMA: sigmoid(relu([m,g] @ Wf + bc) @ cW2 + cb2)
// ---------------------------------------------------------------------------
__global__ __launch_bounds__(256) void k_cls(const unsigned short* __restrict__ mb,
                                             const unsigned short* __restrict__ gb,
                                             const unsigned short* __restrict__ Wf,
                                             const float* __restrict__ bc,
                                             const float* __restrict__ cW2,
                                             const float* __restrict__ cb2,
                                             float* __restrict__ out, int N) {
    int lane = threadIdx.x & 63;
    int wid  = (blockIdx.x * blockDim.x + threadIdx.x) >> 6;
    int nwav = (gridDim.x * blockDim.x) >> 6;
    int col = lane & 15, g4 = lane >> 4;

    short8v Bf[4][4];
#pragma unroll
    for (int ks = 0; ks < 4; ++ks)
#pragma unroll
        for (int cb = 0; cb < 4; ++cb) {
            union { short8v v; unsigned short u[8]; } bu;
#pragma unroll
            for (int j = 0; j < 8; ++j)
                bu.u[j] = Wf[(ks * 32 + g4 * 8 + j) * 64 + cb * 16 + col];
            Bf[ks][cb] = bu.v;
        }
    float w2v[4], bcv[4];
#pragma unroll
    for (int cb = 0; cb < 4; ++cb) { w2v[cb] = cW2[cb * 16 + col]; bcv[cb] = bc[cb * 16 + col]; }
    float cb2v = cb2[0];

    int ntile = (N + 15) >> 4;
    for (int t = wid; t < ntile; t += nwav) {
        int n0 = t * 16;
        int node = n0 + col; if (node >= N) node = N - 1;
        const unsigned short* mr = mb + (size_t)node * 64;
        const unsigned short* gr = gb + (size_t)node * 64;
        f32x4 acc0 = {0.f, 0.f, 0.f, 0.f}, acc1 = acc0, acc2 = acc0, acc3 = acc0;
#pragma unroll
        for (int ks = 0; ks < 4; ++ks) {
            short8v a = (ks < 2)
                ? *reinterpret_cast<const short8v*>(mr + ks * 32 + g4 * 8)
                : *reinterpret_cast<const short8v*>(gr + (ks - 2) * 32 + g4 * 8);
            acc0 = __builtin_amdgcn_mfma_f32_16x16x32_bf16(a, Bf[ks][0], acc0, 0, 0, 0);
            acc1 = __builtin_amdgcn_mfma_f32_16x16x32_bf16(a, Bf[ks][1], acc1, 0, 0, 0);
            acc2 = __builtin_amdgcn_mfma_f32_16x16x32_bf16(a, Bf[ks][2], acc2, 0, 0, 0);
            acc3 = __builtin_amdgcn_mfma_f32_16x16x32_bf16(a, Bf[ks][3], acc3, 0, 0, 0);
        }
        float z[4] = {0.f, 0.f, 0.f, 0.f};
#define CLS_EPI(CB, ACC)                                                   \
        {                                                                  \
            _Pragma("unroll")                                              \
            for (int i = 0; i < 4; ++i)                                    \
                z[i] = fmaf(fmaxf(ACC[i] + bcv[CB], 0.f), w2v[CB], z[i]);  \
        }
        CLS_EPI(0, acc0) CLS_EPI(1, acc1) CLS_EPI(2, acc2) CLS_EPI(3, acc3)
#undef CLS_EPI
#pragma unroll
        for (int i = 0; i < 4; ++i) {
            z[i] += __shfl_xor(z[i], 1); z[i] += __shfl_xor(z[i], 2);
            z[i] += __shfl_xor(z[i], 4); z[i] += __shfl_xor(z[i], 8);
        }
        if (col == 0) {
#pragma unroll
            for (int i = 0; i < 4; ++i) {
                int r = n0 + g4 * 4 + i;
                if (r < N) out[r] = 1.f / (1.f + __expf(-(z[i] + cb2v)));
            }
        }
    }
}

// ---------------------------------------------------------------------------
extern "C" void kernel_launch(void* const* d_in, const int* in_sizes, int n_in,
                              void* d_out, int out_size, void* d_ws, size_t ws_size,
                              hipStream_t stream) {
    const float* td   = (const float*)d_in[0];
    const float* x    = (const float*)d_in[1];
    const int*   ei   = (const int*)d_in[2];
    const float* tW1  = (const float*)d_in[3];
    const float* tb1  = (const float*)d_in[4];
    const float* tW2  = (const float*)d_in[5];
    const float* tb2  = (const float*)d_in[6];
    const float* gW1  = (const float*)d_in[7];
    const float* ga1s = (const float*)d_in[8];
    const float* ga1d = (const float*)d_in[9];
    const float* gb1  = (const float*)d_in[10];
    const float* gW2  = (const float*)d_in[11];
    const float* ga2s = (const float*)d_in[12];
    const float* ga2d = (const float*)d_in[13];
    const float* gb2  = (const float*)d_in[14];
    const float* cW1  = (const float*)d_in[15];
    const float* cb1  = (const float*)d_in[16];
    const float* cW2  = (const float*)d_in[17];
    const float* cb2  = (const float*)d_in[18];

    int N = in_sizes[1] / 10;
    int E = in_sizes[2] / 2;

    float* fws = (float*)d_ws;
    unsigned short* mb16   = (unsigned short*)fws;                    // [N,64] bf16
    unsigned short* h1b    = (unsigned short*)(fws + (size_t)N * 32); // [N,128] bf16
    unsigned short* out1b  = (unsigned short*)(fws + (size_t)N * 96); // [N,128] bf16
    float* a1s   = fws + (size_t)N * 160;
    float* a1d   = fws + (size_t)N * 164;
    unsigned short* h2b = h1b;       // reuse (h1 dead after k_g1b)  [N,64] bf16
    float* a2s   = a1s;              // reuse
    float* a2d   = a1d;              // reuse
    unsigned short* gb16 = out1b;    // reuse (out1 dead after k_g2a) [N,64] bf16

    int* ib       = (int*)(fws + (size_t)N * 168);
    int* counts   = ib;
    int* rowptr   = ib + N;
    int* nxt      = ib + 2 * N + 1;
    int* partials = ib + 3 * N + 1;
    int* col      = ib + 3 * N + 1 + 128;

    unsigned short* Wf = (unsigned short*)(col + E);
    float* bcf = (float*)(Wf + 8192);

    hipMemsetAsync(counts, 0, (size_t)N * sizeof(int), stream);

    int NB = (N + 1023) / 1024;
    int range = (N + SC_P - 1) / SC_P;
    int nb4   = (N + 3) / 4;
    int ntile = (N + 15) / 16;
    int nbt   = (ntile + 3) / 4;

    k_pre     <<<2048, 256, 0, stream>>>(ei, counts, x, gW1, ga1s, ga1d,
                                         h1b, a1s, a1d, N, E);
    k_temporal<<<2048, 256, 0, stream>>>(td, tW1, tb1,
                                         tW2, cW1, tb2, cb1, Wf, bcf, mb16, N);
    k_scan1  <<<NB, 1024, 0, stream>>>(counts, rowptr, partials, N);
    k_scan3  <<<(N + 1 + 255) / 256, 256, 0, stream>>>(rowptr, partials, nxt, N);
    k_scatter<<<(E + 256 * SC_K - 1) / (256 * SC_K), 256, 0, stream>>>(ei, nxt, col, E, range);

    k_g1b<<<nb4, 256, 0, stream>>>(rowptr, col, (const unsigned int*)h1b, a1s, a1d, gb1,
                                   (unsigned int*)out1b, N);
    k_g2a<<<nbt, 256, 0, stream>>>(out1b, gW2, ga2s, ga2d, h2b, a2s, a2d, N);
    k_g2b<<<nb4, 256, 0, stream>>>(rowptr, col, (const unsigned int*)h2b, a2s, a2d, gb2,
                                   (unsigned int*)gb16, N);
    k_cls<<<nbt, 256, 0, stream>>>(mb16, gb16, Wf, bcf, cW2, cb2, (float*)d_out, N);
}

// Round 16
// 394.989 us; speedup vs baseline: 1.0555x; 1.0555x over previous
//
#include <hip/hip_runtime.h>
#include <hip/hip_bf16.h>

#define DEV_INLINE __device__ __forceinline__

typedef __attribute__((ext_vector_type(8))) short short8v;
typedef __attribute__((ext_vector_type(4))) float f32x4;

DEV_INLINE float lrelu(float v) { return fmaxf(v, 0.2f * v); }

DEV_INLINE unsigned int cvt_pk_bf16(float lo, float hi) {
    unsigned int r;
    asm("v_cvt_pk_bf16_f32 %0, %1, %2" : "=v"(r) : "v"(lo), "v"(hi));
    return r;
}

DEV_INLINE unsigned short f2bf_rne(float f) {
    unsigned int b = __float_as_uint(f);
    return (unsigned short)((b + 0x7FFFu + ((b >> 16) & 1u)) >> 16);
}

DEV_INLINE unsigned int pack_bf16(float lo, float hi) {
    return (unsigned int)f2bf_rne(lo) | ((unsigned int)f2bf_rne(hi) << 16);
}

DEV_INLINE float bf_lo(unsigned int u) { return __uint_as_float(u << 16); }
DEV_INLINE float bf_hi(unsigned int u) { return __uint_as_float(u & 0xFFFF0000u); }

// ---------------------------------------------------------------------------
// Zero-fill for counts (hipMemsetAsync's fillBufferAligned path measured
// ~113us for 400KB (~3.6 GB/s) inside the captured graph — pathological).
// ---------------------------------------------------------------------------
__global__ void k_zero(int* __restrict__ p, int n) {
    int i = blockIdx.x * blockDim.x + threadIdx.x;
    int stride = gridDim.x * blockDim.x;
    for (; i < n; i += stride) p[i] = 0;
}

// ---------------------------------------------------------------------------
// CSR scan kernels
// ---------------------------------------------------------------------------
__global__ __launch_bounds__(1024) void k_scan1(const int* __restrict__ counts,
                                                int* __restrict__ rowptr,
                                                int* __restrict__ partials, int N) {
    __shared__ int sd[1024];
    int li = threadIdx.x;
    int i  = blockIdx.x * 1024 + li;
    int v  = (i < N) ? counts[i] : 0;
    sd[li] = v;
    __syncthreads();
    for (int off = 1; off < 1024; off <<= 1) {
        int t = (li >= off) ? sd[li - off] : 0;
        __syncthreads();
        sd[li] += t;
        __syncthreads();
    }
    int inc = sd[li];
    if (i < N) rowptr[i + 1] = inc;
    if (li == 1023) partials[blockIdx.x] = inc;   // raw chunk totals
}

__global__ void k_scan3(int* __restrict__ rowptr, const int* __restrict__ partials,
                        int* __restrict__ nxt, int N) {
    int i = blockIdx.x * blockDim.x + threadIdx.x;
    if (i > N) return;
    int v;
    if (i == 0) { v = 0; rowptr[0] = 0; }
    else {
        int blk = (i - 1) >> 10;
        int pp = 0;
        for (int b = 0; b < blk; ++b) pp += partials[b];
        v = rowptr[i] + pp;
        rowptr[i] = v;
    }
    if (i < N) nxt[i] = v;
}

#define SC_K 8
#define SC_P 16
__global__ __launch_bounds__(256) void k_scatter(const int* __restrict__ ei,
                                                 int* __restrict__ nxt,
                                                 int* __restrict__ col,
                                                 int E, int range) {
    int t = threadIdx.x;
    int base = blockIdx.x * (256 * SC_K);
    int s[SC_K], d[SC_K];
#pragma unroll
    for (int k = 0; k < SC_K; ++k) {
        int e = base + k * 256 + t;
        bool v = (e < E);
        s[k] = v ? ei[e] : 0;
        d[k] = v ? ei[E + e] : -1;
    }
    int lo = 0;
    for (int p = 0; p < SC_P; ++p, lo += range) {
        int hi = lo + range;
#pragma unroll
        for (int k = 0; k < SC_K; ++k) {
            if (d[k] >= lo && d[k] < hi) {
                int pos = atomicAdd(&nxt[d[k]], 1);
                col[pos] = s[k];
            }
        }
        __syncthreads();
    }
}

// ---------------------------------------------------------------------------
// Per-node temporal compute from an LDS slot (512 floats). MFMA 16x16x32.
// ---------------------------------------------------------------------------
DEV_INLINE void temporal_node(const float* wb, int col, int g, const short8v* B,
                              int lane, unsigned short* mb, size_t n) {
    float sum0 = 0.f, sum1 = 0.f, sum2 = 0.f, sum3 = 0.f;
#pragma unroll
    for (int tt = 0; tt < 4; ++tt) {
        int t = tt * 16 + col;
        bool valid = (t < 50);
        float x0 = 0.f, x1 = 0.f, x2 = 0.f, x3 = 0.f;
        float x4 = 0.f, x5 = 0.f, x6 = 0.f, x7 = 0.f;
        const float* rp = wb + t * 10;
        if (g == 0 && valid) {
            float2 p0 = *reinterpret_cast<const float2*>(rp);
            float2 p1 = *reinterpret_cast<const float2*>(rp + 2);
            float2 p2 = *reinterpret_cast<const float2*>(rp + 4);
            float2 p3 = *reinterpret_cast<const float2*>(rp + 6);
            x0 = p0.x; x1 = p0.y; x2 = p1.x; x3 = p1.y;
            x4 = p2.x; x5 = p2.y; x6 = p3.x; x7 = p3.y;
        } else if (g == 1 && valid) {
            float2 p4 = *reinterpret_cast<const float2*>(rp + 8);
            x0 = p4.x; x1 = p4.y; x2 = 1.0f;
        }
        union { short8v v; unsigned int w[4]; } au;
        au.w[0] = cvt_pk_bf16(x0, x1);
        au.w[1] = cvt_pk_bf16(x2, x3);
        au.w[2] = cvt_pk_bf16(x4, x5);
        au.w[3] = cvt_pk_bf16(x6, x7);

        f32x4 z = {0.f, 0.f, 0.f, 0.f};
        f32x4 c0 = __builtin_amdgcn_mfma_f32_16x16x32_bf16(au.v, B[0], z, 0, 0, 0);
        f32x4 c1 = __builtin_amdgcn_mfma_f32_16x16x32_bf16(au.v, B[1], z, 0, 0, 0);
        f32x4 c2 = __builtin_amdgcn_mfma_f32_16x16x32_bf16(au.v, B[2], z, 0, 0, 0);
        f32x4 c3 = __builtin_amdgcn_mfma_f32_16x16x32_bf16(au.v, B[3], z, 0, 0, 0);
#pragma unroll
        for (int i = 0; i < 4; ++i) {
            sum0 += fmaxf(c0[i], 0.f);
            sum1 += fmaxf(c1[i], 0.f);
            sum2 += fmaxf(c2[i], 0.f);
            sum3 += fmaxf(c3[i], 0.f);
        }
    }
    sum0 += __shfl_xor(sum0, 16); sum0 += __shfl_xor(sum0, 32);
    sum1 += __shfl_xor(sum1, 16); sum1 += __shfl_xor(sum1, 32);
    sum2 += __shfl_xor(sum2, 16); sum2 += __shfl_xor(sum2, 32);
    sum3 += __shfl_xor(sum3, 16); sum3 += __shfl_xor(sum3, 32);
    float mv = (g == 0) ? sum0 : (g == 1) ? sum1 : (g == 2) ? sum2 : sum3;
    mb[n * 64 + lane] = f2bf_rne(mv * 0.02f);
}

// ---------------------------------------------------------------------------
// Temporal encoder (+ folded edge-count histogram + classifier-weight fuse).
// Static double buffer, 2-node unrolled loop, distance-2 register staging.
// ---------------------------------------------------------------------------
__global__ __launch_bounds__(256) void k_temporal(const float* __restrict__ td,
                                                  const float* __restrict__ tW1,
                                                  const float* __restrict__ tb1,
                                                  const int* __restrict__ ei,
                                                  int* __restrict__ counts,
                                                  const float* __restrict__ tW2,
                                                  const float* __restrict__ cW1,
                                                  const float* __restrict__ tb2,
                                                  const float* __restrict__ cb1,
                                                  unsigned short* __restrict__ Wf,
                                                  float* __restrict__ bcf,
                                                  unsigned short* __restrict__ mb,
                                                  int N, int E) {
    __shared__ float b0lds[4][512];
    __shared__ float b1lds[4][512];
    int tid = threadIdx.x, lane = tid & 63, wv = tid >> 6;
    int gid = blockIdx.x * 256 + tid;

    // ---- folded k_count ----
    int estr = gridDim.x * 256;
    for (int e = gid; e < E; e += estr) atomicAdd(&counts[ei[E + e]], 1);

    // ---- folded k_fuse ----
    if (gid < 4096) {
        int i = gid >> 6, c = gid & 63;
        float s = 0.f;
#pragma unroll 8
        for (int k = 0; k < 64; ++k) s = fmaf(tW2[i * 64 + k], cW1[k * 64 + c], s);
        Wf[gid] = f2bf_rne(s);
    } else if (gid < 8192) {
        Wf[gid] = f2bf_rne(cW1[gid]);
    } else if (gid < 8256) {
        int c = gid - 8192;
        float s = cb1[c];
#pragma unroll 8
        for (int k = 0; k < 64; ++k) s = fmaf(tb2[k], cW1[k * 64 + c], s);
        bcf[c] = s;
    }

    int wid  = gid >> 6;
    int nwav = (gridDim.x * 256) >> 6;
    int col  = lane & 15;
    int g    = lane >> 4;

    int chunk = (N + nwav - 1) / nwav;
    int n0 = wid * chunk;
    int n1 = min(n0 + chunk, N);
    if (n0 >= n1) return;
    int cnt = n1 - n0;

    // B-frags (bias folded at k=10)
    short8v B[4];
#pragma unroll
    for (int cb = 0; cb < 4; ++cb) {
        union { short8v v; unsigned short u[8]; } bu;
#pragma unroll
        for (int j = 0; j < 8; ++j) {
            int f = g * 8 + j;
            int c = cb * 16 + col;
            float w = (f < 10) ? tW1[f * 64 + c] : ((f == 10) ? tb1[c] : 0.f);
            bu.u[j] = f2bf_rne(w);
        }
        B[cb] = bu.v;
    }

    float* buf0 = &b0lds[wv][0];
    float* buf1 = &b1lds[wv][0];
    float4 zero4 = make_float4(0.f, 0.f, 0.f, 0.f);

#define LOADROW(J, A, Bv)                                                      \
    {                                                                          \
        int nn = n0 + (J); if (nn > n1 - 1) nn = n1 - 1;                       \
        const float4* rr = reinterpret_cast<const float4*>(td + (size_t)nn * 500); \
        A = rr[lane];                                                          \
        Bv = (lane < 61) ? rr[64 + lane] : zero4;                              \
    }
#define WRITEBUF(BUF, A, Bv)                                                   \
    {                                                                          \
        *reinterpret_cast<float4*>((BUF) + 4 * lane) = A;                      \
        if (lane < 61) *reinterpret_cast<float4*>((BUF) + 256 + 4 * lane) = Bv;\
    }

    float4 aA, bA, aB, bB;
    LOADROW(0, aA, bA)
    LOADROW(1, aB, bB)
    WRITEBUF(buf0, aA, bA)
    LOADROW(2, aA, bA)
    WRITEBUF(buf1, aB, bB)
    LOADROW(3, aB, bB)

    int i = 0;
    for (; i + 1 < cnt; i += 2) {
        temporal_node(buf0, col, g, B, lane, mb, (size_t)(n0 + i));
        WRITEBUF(buf0, aA, bA)
        LOADROW(i + 4, aA, bA)
        temporal_node(buf1, col, g, B, lane, mb, (size_t)(n0 + i + 1));
        WRITEBUF(buf1, aB, bB)
        LOADROW(i + 5, aB, bB)
    }
    if (i < cnt)
        temporal_node(buf0, col, g, B, lane, mb, (size_t)(n0 + i));
#undef LOADROW
#undef WRITEBUF
}

// ---------------------------------------------------------------------------
// GATConv1 projection + attention scores. h1b bf16 [n,128], a1s/a1d fp32 [n,4]
// ---------------------------------------------------------------------------
__global__ __launch_bounds__(256) void k_g1a(const float* __restrict__ x,
                                             const float* __restrict__ gW1,
                                             const float* __restrict__ as_w,
                                             const float* __restrict__ ad_w,
                                             unsigned short* __restrict__ h1b,
                                             float* __restrict__ a1s,
                                             float* __restrict__ a1d, int N) {
    int tid = threadIdx.x, lane = tid & 63;
    int n0 = blockIdx.x * 4 + (tid >> 6);
    int n  = __builtin_amdgcn_readfirstlane(n0 < N ? n0 : N - 1);

    float wa[10], wb[10];
#pragma unroll
    for (int i = 0; i < 10; ++i) { wa[i] = gW1[i * 128 + lane]; wb[i] = gW1[i * 128 + 64 + lane]; }
    const float* xp = x + (size_t)n * 10;
    float ha = 0.f, hb = 0.f;
#pragma unroll
    for (int i = 0; i < 10; ++i) { float xv = xp[i]; ha = fmaf(xv, wa[i], ha); hb = fmaf(xv, wb[i], hb); }

    int c = lane & 31;
    int headA = lane >> 5;
    float ps_a = ha * as_w[headA * 32 + c];
    float ps_b = hb * as_w[(headA + 2) * 32 + c];
    float pd_a = ha * ad_w[headA * 32 + c];
    float pd_b = hb * ad_w[(headA + 2) * 32 + c];
#pragma unroll
    for (int m = 1; m < 32; m <<= 1) {
        ps_a += __shfl_xor(ps_a, m); ps_b += __shfl_xor(ps_b, m);
        pd_a += __shfl_xor(pd_a, m); pd_b += __shfl_xor(pd_b, m);
    }
    if (n0 < N) {
        h1b[(size_t)n * 128 + lane]      = f2bf_rne(ha);
        h1b[(size_t)n * 128 + 64 + lane] = f2bf_rne(hb);
        if (c == 0) {
            a1s[n * 4 + headA]     = ps_a;
            a1s[n * 4 + 2 + headA] = ps_b;
            a1d[n * 4 + headA]     = pd_a;
            a1d[n * 4 + 2 + headA] = pd_b;
        }
    }
}

// ---------------------------------------------------------------------------
// GATConv1 aggregation. Quarter-wave per edge stream (4 streams x 16 lanes);
// lane owns 8 channels via uint4. Serial chain ~deg/4; combine shfl_xor(16,32).
// ---------------------------------------------------------------------------
__global__ __launch_bounds__(256) void k_g1b(const int* __restrict__ rowptr,
                                             const int* __restrict__ col,
                                             const unsigned int* __restrict__ h1u,
                                             const float* __restrict__ a1s,
                                             const float* __restrict__ a1d,
                                             const float* __restrict__ gb1,
                                             unsigned int* __restrict__ out1u, int N) {
    int tid = threadIdx.x, lane = tid & 63;
    int n0 = blockIdx.x * 4 + (tid >> 6);
    int n  = __builtin_amdgcn_readfirstlane(n0 < N ? n0 : N - 1);

    int start = rowptr[n], end = rowptr[n + 1];
    int q = lane >> 4, c = lane & 15;     // stream q; channels 8c..8c+7
    int hsel = c >> 2;                    // head
    float advh = a1d[n * 4 + hsel];
    const uint4* h1q = reinterpret_cast<const uint4*>(h1u);

    float den = 0.f;
    float a0 = 0.f, a1v = 0.f, a2v = 0.f, a3v = 0.f;
    float a4 = 0.f, a5 = 0.f, a6 = 0.f, a7 = 0.f;
    if (q == 0) {                         // self loop on stream 0
        float w = __expf(lrelu(a1s[n * 4 + hsel] + advh));
        uint4 u = h1q[(size_t)n * 16 + c];
        den = w;
        a0 = w * bf_lo(u.x); a1v = w * bf_hi(u.x);
        a2v = w * bf_lo(u.y); a3v = w * bf_hi(u.y);
        a4 = w * bf_lo(u.z); a5 = w * bf_hi(u.z);
        a6 = w * bf_lo(u.w); a7 = w * bf_hi(u.w);
    }
    int e = start + q;
    for (; e + 4 < end; e += 8) {         // 2-edge unroll per stream
        int s0 = col[e], s1 = col[e + 4];
        float q0 = a1s[s0 * 4 + hsel];
        float q1 = a1s[s1 * 4 + hsel];
        uint4 u0 = h1q[(size_t)s0 * 16 + c];
        uint4 u1 = h1q[(size_t)s1 * 16 + c];
        float w0 = __expf(lrelu(q0 + advh));
        float w1 = __expf(lrelu(q1 + advh));
        den += w0 + w1;
        a0 = fmaf(w0, bf_lo(u0.x), a0); a1v = fmaf(w0, bf_hi(u0.x), a1v);
        a2v = fmaf(w0, bf_lo(u0.y), a2v); a3v = fmaf(w0, bf_hi(u0.y), a3v);
        a4 = fmaf(w0, bf_lo(u0.z), a4); a5 = fmaf(w0, bf_hi(u0.z), a5);
        a6 = fmaf(w0, bf_lo(u0.w), a6); a7 = fmaf(w0, bf_hi(u0.w), a7);
        a0 = fmaf(w1, bf_lo(u1.x), a0); a1v = fmaf(w1, bf_hi(u1.x), a1v);
        a2v = fmaf(w1, bf_lo(u1.y), a2v); a3v = fmaf(w1, bf_hi(u1.y), a3v);
        a4 = fmaf(w1, bf_lo(u1.z), a4); a5 = fmaf(w1, bf_hi(u1.z), a5);
        a6 = fmaf(w1, bf_lo(u1.w), a6); a7 = fmaf(w1, bf_hi(u1.w), a7);
    }
    if (e < end) {
        int s = col[e];
        float qv = a1s[s * 4 + hsel];
        uint4 u = h1q[(size_t)s * 16 + c];
        float w = __expf(lrelu(qv + advh));
        den += w;
        a0 = fmaf(w, bf_lo(u.x), a0); a1v = fmaf(w, bf_hi(u.x), a1v);
        a2v = fmaf(w, bf_lo(u.y), a2v); a3v = fmaf(w, bf_hi(u.y), a3v);
        a4 = fmaf(w, bf_lo(u.z), a4); a5 = fmaf(w, bf_hi(u.z), a5);
        a6 = fmaf(w, bf_lo(u.w), a6); a7 = fmaf(w, bf_hi(u.w), a7);
    }
#define RED2(v) v += __shfl_xor(v, 16); v += __shfl_xor(v, 32);
    RED2(den) RED2(a0) RED2(a1v) RED2(a2v) RED2(a3v)
    RED2(a4) RED2(a5) RED2(a6) RED2(a7)
#undef RED2

    if (n0 < N && lane < 16) {
        float inv = 1.f / den;
        float v0 = a0 * inv + gb1[8 * c + 0];
        float v1 = a1v * inv + gb1[8 * c + 1];
        float v2 = a2v * inv + gb1[8 * c + 2];
        float v3 = a3v * inv + gb1[8 * c + 3];
        float v4 = a4 * inv + gb1[8 * c + 4];
        float v5 = a5 * inv + gb1[8 * c + 5];
        float v6 = a6 * inv + gb1[8 * c + 6];
        float v7 = a7 * inv + gb1[8 * c + 7];
        v0 = (v0 > 0.f) ? v0 : (__expf(v0) - 1.f);
        v1 = (v1 > 0.f) ? v1 : (__expf(v1) - 1.f);
        v2 = (v2 > 0.f) ? v2 : (__expf(v2) - 1.f);
        v3 = (v3 > 0.f) ? v3 : (__expf(v3) - 1.f);
        v4 = (v4 > 0.f) ? v4 : (__expf(v4) - 1.f);
        v5 = (v5 > 0.f) ? v5 : (__expf(v5) - 1.f);
        v6 = (v6 > 0.f) ? v6 : (__expf(v6) - 1.f);
        v7 = (v7 > 0.f) ? v7 : (__expf(v7) - 1.f);
        uint4 o;
        o.x = pack_bf16(v0, v1); o.y = pack_bf16(v2, v3);
        o.z = pack_bf16(v4, v5); o.w = pack_bf16(v6, v7);
        *reinterpret_cast<uint4*>(out1u + (size_t)n * 64 + 4 * c) = o;
    }
}

// ---------------------------------------------------------------------------
// GATConv2 projection via MFMA: h2 = out1 @ gW2 (bf16 in/out) + scores.
// ---------------------------------------------------------------------------
__global__ __launch_bounds__(256) void k_g2a(const unsigned short* __restrict__ out1b,
                                             const float* __restrict__ gW2,
                                             const float* __restrict__ a2sw,
                                             const float* __restrict__ a2dw,
                                             unsigned short* __restrict__ h2b,
                                             float* __restrict__ a2s,
                                             float* __restrict__ a2d, int N) {
    int lane = threadIdx.x & 63;
    int wid  = (blockIdx.x * blockDim.x + threadIdx.x) >> 6;
    int nwav = (gridDim.x * blockDim.x) >> 6;
    int col = lane & 15, g4 = lane >> 4;

    short8v Bf[4][4];
#pragma unroll
    for (int ks = 0; ks < 4; ++ks)
#pragma unroll
        for (int cb = 0; cb < 4; ++cb) {
            union { short8v v; unsigned short u[8]; } bu;
#pragma unroll
            for (int j = 0; j < 8; ++j)
                bu.u[j] = f2bf_rne(gW2[(ks * 32 + g4 * 8 + j) * 64 + cb * 16 + col]);
            Bf[ks][cb] = bu.v;
        }
    float asv[4], adv[4];
#pragma unroll
    for (int cb = 0; cb < 4; ++cb) { asv[cb] = a2sw[cb * 16 + col]; adv[cb] = a2dw[cb * 16 + col]; }

    int ntile = (N + 15) >> 4;
    for (int t = wid; t < ntile; t += nwav) {
        int n0 = t * 16;
        int node = n0 + col; if (node >= N) node = N - 1;
        const unsigned short* xr = out1b + (size_t)node * 128;
        f32x4 acc0 = {0.f, 0.f, 0.f, 0.f}, acc1 = acc0, acc2 = acc0, acc3 = acc0;
#pragma unroll
        for (int ks = 0; ks < 4; ++ks) {
            short8v a = *reinterpret_cast<const short8v*>(xr + ks * 32 + g4 * 8);
            acc0 = __builtin_amdgcn_mfma_f32_16x16x32_bf16(a, Bf[ks][0], acc0, 0, 0, 0);
            acc1 = __builtin_amdgcn_mfma_f32_16x16x32_bf16(a, Bf[ks][1], acc1, 0, 0, 0);
            acc2 = __builtin_amdgcn_mfma_f32_16x16x32_bf16(a, Bf[ks][2], acc2, 0, 0, 0);
            acc3 = __builtin_amdgcn_mfma_f32_16x16x32_bf16(a, Bf[ks][3], acc3, 0, 0, 0);
        }
        float ps[4] = {0.f, 0.f, 0.f, 0.f}, pd[4] = {0.f, 0.f, 0.f, 0.f};
#define G2A_EPI(CB, ACC)                                                      \
        {                                                                     \
            _Pragma("unroll")                                                 \
            for (int i = 0; i < 4; ++i) {                                     \
                float v = ACC[i];                                             \
                int r = n0 + g4 * 4 + i;                                      \
                if (r < N) h2b[(size_t)r * 64 + CB * 16 + col] = f2bf_rne(v); \
                ps[i] = fmaf(v, asv[CB], ps[i]);                              \
                pd[i] = fmaf(v, adv[CB], pd[i]);                              \
            }                                                                 \
        }
        G2A_EPI(0, acc0) G2A_EPI(1, acc1) G2A_EPI(2, acc2) G2A_EPI(3, acc3)
#undef G2A_EPI
#pragma unroll
        for (int i = 0; i < 4; ++i) {
            ps[i] += __shfl_xor(ps[i], 1); ps[i] += __shfl_xor(ps[i], 2);
            ps[i] += __shfl_xor(ps[i], 4); ps[i] += __shfl_xor(ps[i], 8);
            pd[i] += __shfl_xor(pd[i], 1); pd[i] += __shfl_xor(pd[i], 2);
            pd[i] += __shfl_xor(pd[i], 4); pd[i] += __shfl_xor(pd[i], 8);
        }
        if (col == 0) {
#pragma unroll
            for (int i = 0; i < 4; ++i) {
                int r = n0 + g4 * 4 + i;
                if (r < N) { a2s[r] = ps[i]; a2d[r] = pd[i]; }
            }
        }
    }
}

// ---------------------------------------------------------------------------
// GATConv2 aggregation. Eighth-wave per edge stream (8 streams x 8 lanes),
// 8 ch/lane via uint4. Chain ~deg/8; combine shfl_xor(8,16,32).
// ---------------------------------------------------------------------------
__global__ __launch_bounds__(256) void k_g2b(const int* __restrict__ rowptr,
                                             const int* __restrict__ col,
                                             const unsigned int* __restrict__ h2u,
                                             const float* __restrict__ a2s,
                                             const float* __restrict__ a2d,
                                             const float* __restrict__ gb2,
                                             unsigned int* __restrict__ gu, int N) {
    int tid = threadIdx.x, lane = tid & 63;
    int n0 = blockIdx.x * 4 + (tid >> 6);
    int n  = __builtin_amdgcn_readfirstlane(n0 < N ? n0 : N - 1);

    int start = rowptr[n], end = rowptr[n + 1];
    int q = lane >> 3, c = lane & 7;     // stream q; channels 8c..8c+7
    float ad = a2d[n];
    const uint4* h2q = reinterpret_cast<const uint4*>(h2u);

    float den = 0.f;
    float a0 = 0.f, a1v = 0.f, a2v = 0.f, a3v = 0.f;
    float a4 = 0.f, a5 = 0.f, a6 = 0.f, a7 = 0.f;
    if (q == 0) {                        // self loop on stream 0
        float w = __expf(lrelu(a2s[n] + ad));
        uint4 u = h2q[(size_t)n * 8 + c];
        den = w;
        a0 = w * bf_lo(u.x); a1v = w * bf_hi(u.x);
        a2v = w * bf_lo(u.y); a3v = w * bf_hi(u.y);
        a4 = w * bf_lo(u.z); a5 = w * bf_hi(u.z);
        a6 = w * bf_lo(u.w); a7 = w * bf_hi(u.w);
    }
    for (int e = start + q; e < end; e += 8) {
        int s = col[e];
        float w = __expf(lrelu(a2s[s] + ad));
        uint4 u = h2q[(size_t)s * 8 + c];
        den += w;
        a0 = fmaf(w, bf_lo(u.x), a0); a1v = fmaf(w, bf_hi(u.x), a1v);
        a2v = fmaf(w, bf_lo(u.y), a2v); a3v = fmaf(w, bf_hi(u.y), a3v);
        a4 = fmaf(w, bf_lo(u.z), a4); a5 = fmaf(w, bf_hi(u.z), a5);
        a6 = fmaf(w, bf_lo(u.w), a6); a7 = fmaf(w, bf_hi(u.w), a7);
    }
#define RED3(v) v += __shfl_xor(v, 8); v += __shfl_xor(v, 16); v += __shfl_xor(v, 32);
    RED3(den) RED3(a0) RED3(a1v) RED3(a2v) RED3(a3v)
    RED3(a4) RED3(a5) RED3(a6) RED3(a7)
#undef RED3

    if (n0 < N && lane < 8) {
        float inv = 1.f / den;
        uint4 o;
        o.x = pack_bf16(a0 * inv + gb2[8 * c + 0], a1v * inv + gb2[8 * c + 1]);
        o.y = pack_bf16(a2v * inv + gb2[8 * c + 2], a3v * inv + gb2[8 * c + 3]);
        o.z = pack_bf16(a4 * inv + gb2[8 * c + 4], a5 * inv + gb2[8 * c + 5]);
        o.w = pack_bf16(a6 * inv + gb2[8 * c + 6], a7 * inv + gb2[8 * c + 7]);
        *reinterpret_cast<uint4*>(gu + (size_t)n * 32 + 4 * c) = o;
    }
}

// ---------------------------------------------------------------------------
// Classifier via MFMA: sigmoid(relu([m,g] @ Wf + bc) @ cW2 + cb2)
// ---------------------------------------------------------------------------
__global__ __launch_bounds__(256) void k_cls(const unsigned short* __restrict__ mb,
                                             const unsigned short* __restrict__ gb,
                                             const unsigned short* __restrict__ Wf,
                                             const float* __restrict__ bc,
                                             const float* __restrict__ cW2,
                                             const float* __restrict__ cb2,
                                             float* __restrict__ out, int N) {
    int lane = threadIdx.x & 63;
    int wid  = (blockIdx.x * blockDim.x + threadIdx.x) >> 6;
    int nwav = (gridDim.x * blockDim.x) >> 6;
    int col = lane & 15, g4 = lane >> 4;

    short8v Bf[4][4];
#pragma unroll
    for (int ks = 0; ks < 4; ++ks)
#pragma unroll
        for (int cb = 0; cb < 4; ++cb) {
            union { short8v v; unsigned short u[8]; } bu;
#pragma unroll
            for (int j = 0; j < 8; ++j)
                bu.u[j] = Wf[(ks * 32 + g4 * 8 + j) * 64 + cb * 16 + col];
            Bf[ks][cb] = bu.v;
        }
    float w2v[4], bcv[4];
#pragma unroll
    for (int cb = 0; cb < 4; ++cb) { w2v[cb] = cW2[cb * 16 + col]; bcv[cb] = bc[cb * 16 + col]; }
    float cb2v = cb2[0];

    int ntile = (N + 15) >> 4;
    for (int t = wid; t < ntile; t += nwav) {
        int n0 = t * 16;
        int node = n0 + col; if (node >= N) node = N - 1;
        const unsigned short* mr = mb + (size_t)node * 64;
        const unsigned short* gr = gb + (size_t)node * 64;
        f32x4 acc0 = {0.f, 0.f, 0.f, 0.f}, acc1 = acc0, acc2 = acc0, acc3 = acc0;
#pragma unroll
        for (int ks = 0; ks < 4; ++ks) {
            short8v a = (ks < 2)
                ? *reinterpret_cast<const short8v*>(mr + ks * 32 + g4 * 8)
                : *reinterpret_cast<const short8v*>(gr + (ks - 2) * 32 + g4 * 8);
            acc0 = __builtin_amdgcn_mfma_f32_16x16x32_bf16(a, Bf[ks][0], acc0, 0, 0, 0);
            acc1 = __builtin_amdgcn_mfma_f32_16x16x32_bf16(a, Bf[ks][1], acc1, 0, 0, 0);
            acc2 = __builtin_amdgcn_mfma_f32_16x16x32_bf16(a, Bf[ks][2], acc2, 0, 0, 0);
            acc3 = __builtin_amdgcn_mfma_f32_16x16x32_bf16(a, Bf[ks][3], acc3, 0, 0, 0);
        }
        float z[4] = {0.f, 0.f, 0.f, 0.f};
#define CLS_EPI(CB, ACC)                                                   \
        {                                                                  \
            _Pragma("unroll")                                              \
            for (int i = 0; i < 4; ++i)                                    \
                z[i] = fmaf(fmaxf(ACC[i] + bcv[CB], 0.f), w2v[CB], z[i]);  \
        }
        CLS_EPI(0, acc0) CLS_EPI(1, acc1) CLS_EPI(2, acc2) CLS_EPI(3, acc3)
#undef CLS_EPI
#pragma unroll
        for (int i = 0; i < 4; ++i) {
            z[i] += __shfl_xor(z[i], 1); z[i] += __shfl_xor(z[i], 2);
            z[i] += __shfl_xor(z[i], 4); z[i] += __shfl_xor(z[i], 8);
        }
        if (col == 0) {
#pragma unroll
            for (int i = 0; i < 4; ++i) {
                int r = n0 + g4 * 4 + i;
                if (r < N) out[r] = 1.f / (1.f + __expf(-(z[i] + cb2v)));
            }
        }
    }
}

// ---------------------------------------------------------------------------
extern "C" void kernel_launch(void* const* d_in, const int* in_sizes, int n_in,
                              void* d_out, int out_size, void* d_ws, size_t ws_size,
                              hipStream_t stream) {
    const float* td   = (const float*)d_in[0];
    const float* x    = (const float*)d_in[1];
    const int*   ei   = (const int*)d_in[2];
    const float* tW1  = (const float*)d_in[3];
    const float* tb1  = (const float*)d_in[4];
    const float* tW2  = (const float*)d_in[5];
    const float* tb2  = (const float*)d_in[6];
    const float* gW1  = (const float*)d_in[7];
    const float* ga1s = (const float*)d_in[8];
    const float* ga1d = (const float*)d_in[9];
    const float* gb1  = (const float*)d_in[10];
    const float* gW2  = (const float*)d_in[11];
    const float* ga2s = (const float*)d_in[12];
    const float* ga2d = (const float*)d_in[13];
    const float* gb2  = (const float*)d_in[14];
    const float* cW1  = (const float*)d_in[15];
    const float* cb1  = (const float*)d_in[16];
    const float* cW2  = (const float*)d_in[17];
    const float* cb2  = (const float*)d_in[18];

    int N = in_sizes[1] / 10;
    int E = in_sizes[2] / 2;

    float* fws = (float*)d_ws;
    unsigned short* mb16   = (unsigned short*)fws;                    // [N,64] bf16
    unsigned short* h1b    = (unsigned short*)(fws + (size_t)N * 32); // [N,128] bf16
    unsigned short* out1b  = (unsigned short*)(fws + (size_t)N * 96); // [N,128] bf16
    float* a1s   = fws + (size_t)N * 160;
    float* a1d   = fws + (size_t)N * 164;
    unsigned short* h2b = h1b;       // reuse (h1 dead after k_g1b)  [N,64] bf16
    float* a2s   = a1s;              // reuse
    float* a2d   = a1d;              // reuse
    unsigned short* gb16 = out1b;    // reuse (out1 dead after k_g2a) [N,64] bf16

    int* ib       = (int*)(fws + (size_t)N * 168);
    int* counts   = ib;
    int* rowptr   = ib + N;
    int* nxt      = ib + 2 * N + 1;
    int* partials = ib + 3 * N + 1;
    int* col      = ib + 3 * N + 1 + 128;

    unsigned short* Wf = (unsigned short*)(col + E);
    float* bcf = (float*)(Wf + 8192);

    int NB = (N + 1023) / 1024;
    int range = (N + SC_P - 1) / SC_P;
    int nb4   = (N + 3) / 4;
    int ntile = (N + 15) / 16;
    int nbt   = (ntile + 3) / 4;

    // custom zero (hipMemsetAsync's fill path measured ~113us for 400KB)
    k_zero<<<256, 256, 0, stream>>>(counts, N);

    k_temporal<<<2048, 256, 0, stream>>>(td, tW1, tb1, ei, counts,
                                         tW2, cW1, tb2, cb1, Wf, bcf, mb16, N, E);
    k_scan1  <<<NB, 1024, 0, stream>>>(counts, rowptr, partials, N);
    k_scan3  <<<(N + 1 + 255) / 256, 256, 0, stream>>>(rowptr, partials, nxt, N);
    k_scatter<<<(E + 256 * SC_K - 1) / (256 * SC_K), 256, 0, stream>>>(ei, nxt, col, E, range);

    k_g1a<<<nb4, 256, 0, stream>>>(x, gW1, ga1s, ga1d, h1b, a1s, a1d, N);
    k_g1b<<<nb4, 256, 0, stream>>>(rowptr, col, (const unsigned int*)h1b, a1s, a1d, gb1,
                                   (unsigned int*)out1b, N);
    k_g2a<<<nbt, 256, 0, stream>>>(out1b, gW2, ga2s, ga2d, h2b, a2s, a2d, N);
    k_g2b<<<nb4, 256, 0, stream>>>(rowptr, col, (const unsigned int*)h2b, a2s, a2d, gb2,
                                   (unsigned int*)gb16, N);
    k_cls<<<nbt, 256, 0, stream>>>(mb16, gb16, Wf, bcf, cW2, cb2, (float*)d_out, N);
}

// Round 17
// 392.669 us; speedup vs baseline: 1.0618x; 1.0059x over previous
//
#include <hip/hip_runtime.h>
#include <hip/hip_bf16.h>

#define DEV_INLINE __device__ __forceinline__

typedef __attribute__((ext_vector_type(8))) short short8v;
typedef __attribute__((ext_vector_type(4))) float f32x4;

DEV_INLINE float lrelu(float v) { return fmaxf(v, 0.2f * v); }

DEV_INLINE unsigned int cvt_pk_bf16(float lo, float hi) {
    unsigned int r;
    asm("v_cvt_pk_bf16_f32 %0, %1, %2" : "=v"(r) : "v"(lo), "v"(hi));
    return r;
}

DEV_INLINE unsigned short f2bf_rne(float f) {
    unsigned int b = __float_as_uint(f);
    return (unsigned short)((b + 0x7FFFu + ((b >> 16) & 1u)) >> 16);
}

DEV_INLINE unsigned int pack_bf16(float lo, float hi) {
    return (unsigned int)f2bf_rne(lo) | ((unsigned int)f2bf_rne(hi) << 16);
}

DEV_INLINE float bf_lo(unsigned int u) { return __uint_as_float(u << 16); }
DEV_INLINE float bf_hi(unsigned int u) { return __uint_as_float(u & 0xFFFF0000u); }

// ---------------------------------------------------------------------------
__global__ void k_zero(int* __restrict__ p, int n) {
    int i = blockIdx.x * blockDim.x + threadIdx.x;
    int stride = gridDim.x * blockDim.x;
    for (; i < n; i += stride) p[i] = 0;
}

// ---------------------------------------------------------------------------
// CSR scan kernels
// ---------------------------------------------------------------------------
__global__ __launch_bounds__(1024) void k_scan1(const int* __restrict__ counts,
                                                int* __restrict__ rowptr,
                                                int* __restrict__ partials, int N) {
    __shared__ int sd[1024];
    int li = threadIdx.x;
    int i  = blockIdx.x * 1024 + li;
    int v  = (i < N) ? counts[i] : 0;
    sd[li] = v;
    __syncthreads();
    for (int off = 1; off < 1024; off <<= 1) {
        int t = (li >= off) ? sd[li - off] : 0;
        __syncthreads();
        sd[li] += t;
        __syncthreads();
    }
    int inc = sd[li];
    if (i < N) rowptr[i + 1] = inc;
    if (li == 1023) partials[blockIdx.x] = inc;   // raw chunk totals
}

__global__ void k_scan3(int* __restrict__ rowptr, const int* __restrict__ partials,
                        int* __restrict__ nxt, int N) {
    int i = blockIdx.x * blockDim.x + threadIdx.x;
    if (i > N) return;
    int v;
    if (i == 0) { v = 0; rowptr[0] = 0; }
    else {
        int blk = (i - 1) >> 10;
        int pp = 0;
        for (int b = 0; b < blk; ++b) pp += partials[b];
        v = rowptr[i] + pp;
        rowptr[i] = v;
    }
    if (i < N) nxt[i] = v;
}

#define SC_K 8
#define SC_P 16
__global__ __launch_bounds__(256) void k_scatter(const int* __restrict__ ei,
                                                 int* __restrict__ nxt,
                                                 int* __restrict__ col,
                                                 int E, int range) {
    int t = threadIdx.x;
    int base = blockIdx.x * (256 * SC_K);
    int s[SC_K], d[SC_K];
#pragma unroll
    for (int k = 0; k < SC_K; ++k) {
        int e = base + k * 256 + t;
        bool v = (e < E);
        s[k] = v ? ei[e] : 0;
        d[k] = v ? ei[E + e] : -1;
    }
    int lo = 0;
    for (int p = 0; p < SC_P; ++p, lo += range) {
        int hi = lo + range;
#pragma unroll
        for (int k = 0; k < SC_K; ++k) {
            if (d[k] >= lo && d[k] < hi) {
                int pos = atomicAdd(&nxt[d[k]], 1);
                col[pos] = s[k];
            }
        }
        __syncthreads();
    }
}

// ---------------------------------------------------------------------------
// Per-node temporal compute from an LDS slot (512 floats). 3 MFMA tiles cover
// t=0..47 (no validity guards); t=48,49 handled as fp32 VALU tail with
// lane=channel weights (saves a full 16-row tile that had only 2 valid rows).
// ---------------------------------------------------------------------------
DEV_INLINE void temporal_node(const float* wb, int col, int g, const short8v* B,
                              const float* w1c, float b1c,
                              int lane, unsigned short* mb, size_t n) {
    float sum0 = 0.f, sum1 = 0.f, sum2 = 0.f, sum3 = 0.f;
#pragma unroll
    for (int tt = 0; tt < 3; ++tt) {
        int t = tt * 16 + col;               // <= 47: always valid
        float x0 = 0.f, x1 = 0.f, x2 = 0.f, x3 = 0.f;
        float x4 = 0.f, x5 = 0.f, x6 = 0.f, x7 = 0.f;
        const float* rp = wb + t * 10;
        if (g == 0) {
            float2 p0 = *reinterpret_cast<const float2*>(rp);
            float2 p1 = *reinterpret_cast<const float2*>(rp + 2);
            float2 p2 = *reinterpret_cast<const float2*>(rp + 4);
            float2 p3 = *reinterpret_cast<const float2*>(rp + 6);
            x0 = p0.x; x1 = p0.y; x2 = p1.x; x3 = p1.y;
            x4 = p2.x; x5 = p2.y; x6 = p3.x; x7 = p3.y;
        } else if (g == 1) {
            float2 p4 = *reinterpret_cast<const float2*>(rp + 8);
            x0 = p4.x; x1 = p4.y; x2 = 1.0f;
        }
        union { short8v v; unsigned int w[4]; } au;
        au.w[0] = cvt_pk_bf16(x0, x1);
        au.w[1] = cvt_pk_bf16(x2, x3);
        au.w[2] = cvt_pk_bf16(x4, x5);
        au.w[3] = cvt_pk_bf16(x6, x7);

        f32x4 z = {0.f, 0.f, 0.f, 0.f};
        f32x4 c0 = __builtin_amdgcn_mfma_f32_16x16x32_bf16(au.v, B[0], z, 0, 0, 0);
        f32x4 c1 = __builtin_amdgcn_mfma_f32_16x16x32_bf16(au.v, B[1], z, 0, 0, 0);
        f32x4 c2 = __builtin_amdgcn_mfma_f32_16x16x32_bf16(au.v, B[2], z, 0, 0, 0);
        f32x4 c3 = __builtin_amdgcn_mfma_f32_16x16x32_bf16(au.v, B[3], z, 0, 0, 0);
#pragma unroll
        for (int i = 0; i < 4; ++i) {
            sum0 += fmaxf(c0[i], 0.f);
            sum1 += fmaxf(c1[i], 0.f);
            sum2 += fmaxf(c2[i], 0.f);
            sum3 += fmaxf(c3[i], 0.f);
        }
    }
    sum0 += __shfl_xor(sum0, 16); sum0 += __shfl_xor(sum0, 32);
    sum1 += __shfl_xor(sum1, 16); sum1 += __shfl_xor(sum1, 32);
    sum2 += __shfl_xor(sum2, 16); sum2 += __shfl_xor(sum2, 32);
    sum3 += __shfl_xor(sum3, 16); sum3 += __shfl_xor(sum3, 32);
    float mv = (g == 0) ? sum0 : (g == 1) ? sum1 : (g == 2) ? sum2 : sum3;

    // fp32 tail for t=48,49 (wave-uniform LDS reads; lane = channel)
    const float* tp = wb + 480;
    float u48 = b1c, u49 = b1c;
#pragma unroll
    for (int i = 0; i < 10; ++i) {
        u48 = fmaf(tp[i],      w1c[i], u48);
        u49 = fmaf(tp[10 + i], w1c[i], u49);
    }
    mv += fmaxf(u48, 0.f) + fmaxf(u49, 0.f);

    mb[n * 64 + lane] = f2bf_rne(mv * 0.02f);
}

// ---------------------------------------------------------------------------
// Temporal encoder (+ folded edge-count histogram + classifier-weight fuse).
// Static double buffer, 2-node unrolled loop, distance-2 register staging.
// ---------------------------------------------------------------------------
__global__ __launch_bounds__(256) void k_temporal(const float* __restrict__ td,
                                                  const float* __restrict__ tW1,
                                                  const float* __restrict__ tb1,
                                                  const int* __restrict__ ei,
                                                  int* __restrict__ counts,
                                                  const float* __restrict__ tW2,
                                                  const float* __restrict__ cW1,
                                                  const float* __restrict__ tb2,
                                                  const float* __restrict__ cb1,
                                                  unsigned short* __restrict__ Wf,
                                                  float* __restrict__ bcf,
                                                  unsigned short* __restrict__ mb,
                                                  int N, int E) {
    __shared__ float b0lds[4][512];
    __shared__ float b1lds[4][512];
    int tid = threadIdx.x, lane = tid & 63, wv = tid >> 6;
    int gid = blockIdx.x * 256 + tid;

    // ---- folded k_count ----
    int estr = gridDim.x * 256;
    for (int e = gid; e < E; e += estr) atomicAdd(&counts[ei[E + e]], 1);

    // ---- folded k_fuse ----
    if (gid < 4096) {
        int i = gid >> 6, c = gid & 63;
        float s = 0.f;
#pragma unroll 8
        for (int k = 0; k < 64; ++k) s = fmaf(tW2[i * 64 + k], cW1[k * 64 + c], s);
        Wf[gid] = f2bf_rne(s);
    } else if (gid < 8192) {
        Wf[gid] = f2bf_rne(cW1[gid]);
    } else if (gid < 8256) {
        int c = gid - 8192;
        float s = cb1[c];
#pragma unroll 8
        for (int k = 0; k < 64; ++k) s = fmaf(tb2[k], cW1[k * 64 + c], s);
        bcf[c] = s;
    }

    int wid  = gid >> 6;
    int nwav = (gridDim.x * 256) >> 6;
    int col  = lane & 15;
    int g    = lane >> 4;

    int chunk = (N + nwav - 1) / nwav;
    int n0 = wid * chunk;
    int n1 = min(n0 + chunk, N);
    if (n0 >= n1) return;
    int cnt = n1 - n0;

    // B-frags (bias folded at k=10)
    short8v B[4];
#pragma unroll
    for (int cb = 0; cb < 4; ++cb) {
        union { short8v v; unsigned short u[8]; } bu;
#pragma unroll
        for (int j = 0; j < 8; ++j) {
            int f = g * 8 + j;
            int c = cb * 16 + col;
            float w = (f < 10) ? tW1[f * 64 + c] : ((f == 10) ? tb1[c] : 0.f);
            bu.u[j] = f2bf_rne(w);
        }
        B[cb] = bu.v;
    }
    // per-lane column weights for the fp32 tail (lane = channel)
    float w1c[10];
#pragma unroll
    for (int i = 0; i < 10; ++i) w1c[i] = tW1[i * 64 + lane];
    float b1c = tb1[lane];

    float* buf0 = &b0lds[wv][0];
    float* buf1 = &b1lds[wv][0];
    float4 zero4 = make_float4(0.f, 0.f, 0.f, 0.f);

#define LOADROW(J, A, Bv)                                                      \
    {                                                                          \
        int nn = n0 + (J); if (nn > n1 - 1) nn = n1 - 1;                       \
        const float4* rr = reinterpret_cast<const float4*>(td + (size_t)nn * 500); \
        A = rr[lane];                                                          \
        Bv = (lane < 61) ? rr[64 + lane] : zero4;                              \
    }
#define WRITEBUF(BUF, A, Bv)                                                   \
    {                                                                          \
        *reinterpret_cast<float4*>((BUF) + 4 * lane) = A;                      \
        if (lane < 61) *reinterpret_cast<float4*>((BUF) + 256 + 4 * lane) = Bv;\
    }

    float4 aA, bA, aB, bB;
    LOADROW(0, aA, bA)
    LOADROW(1, aB, bB)
    WRITEBUF(buf0, aA, bA)
    LOADROW(2, aA, bA)
    WRITEBUF(buf1, aB, bB)
    LOADROW(3, aB, bB)

    int i = 0;
    for (; i + 1 < cnt; i += 2) {
        temporal_node(buf0, col, g, B, w1c, b1c, lane, mb, (size_t)(n0 + i));
        WRITEBUF(buf0, aA, bA)
        LOADROW(i + 4, aA, bA)
        temporal_node(buf1, col, g, B, w1c, b1c, lane, mb, (size_t)(n0 + i + 1));
        WRITEBUF(buf1, aB, bB)
        LOADROW(i + 5, aB, bB)
    }
    if (i < cnt)
        temporal_node(buf0, col, g, B, w1c, b1c, lane, mb, (size_t)(n0 + i));
#undef LOADROW
#undef WRITEBUF
}

// ---------------------------------------------------------------------------
// GATConv1 projection + attention scores. h1b bf16 [n,128], a1s/a1d fp32 [n,4]
// ---------------------------------------------------------------------------
__global__ __launch_bounds__(256) void k_g1a(const float* __restrict__ x,
                                             const float* __restrict__ gW1,
                                             const float* __restrict__ as_w,
                                             const float* __restrict__ ad_w,
                                             unsigned short* __restrict__ h1b,
                                             float* __restrict__ a1s,
                                             float* __restrict__ a1d, int N) {
    int tid = threadIdx.x, lane = tid & 63;
    int n0 = blockIdx.x * 4 + (tid >> 6);
    int n  = __builtin_amdgcn_readfirstlane(n0 < N ? n0 : N - 1);

    float wa[10], wb[10];
#pragma unroll
    for (int i = 0; i < 10; ++i) { wa[i] = gW1[i * 128 + lane]; wb[i] = gW1[i * 128 + 64 + lane]; }
    const float* xp = x + (size_t)n * 10;
    float ha = 0.f, hb = 0.f;
#pragma unroll
    for (int i = 0; i < 10; ++i) { float xv = xp[i]; ha = fmaf(xv, wa[i], ha); hb = fmaf(xv, wb[i], hb); }

    int c = lane & 31;
    int headA = lane >> 5;
    float ps_a = ha * as_w[headA * 32 + c];
    float ps_b = hb * as_w[(headA + 2) * 32 + c];
    float pd_a = ha * ad_w[headA * 32 + c];
    float pd_b = hb * ad_w[(headA + 2) * 32 + c];
#pragma unroll
    for (int m = 1; m < 32; m <<= 1) {
        ps_a += __shfl_xor(ps_a, m); ps_b += __shfl_xor(ps_b, m);
        pd_a += __shfl_xor(pd_a, m); pd_b += __shfl_xor(pd_b, m);
    }
    if (n0 < N) {
        h1b[(size_t)n * 128 + lane]      = f2bf_rne(ha);
        h1b[(size_t)n * 128 + 64 + lane] = f2bf_rne(hb);
        if (c == 0) {
            a1s[n * 4 + headA]     = ps_a;
            a1s[n * 4 + 2 + headA] = ps_b;
            a1d[n * 4 + headA]     = pd_a;
            a1d[n * 4 + 2 + headA] = pd_b;
        }
    }
}

// ---------------------------------------------------------------------------
// GATConv1 aggregation. Quarter-wave per edge stream (4 streams x 16 lanes);
// lane owns 8 channels via uint4. Serial chain ~deg/4; combine shfl_xor(16,32).
// ---------------------------------------------------------------------------
__global__ __launch_bounds__(256) void k_g1b(const int* __restrict__ rowptr,
                                             const int* __restrict__ col,
                                             const unsigned int* __restrict__ h1u,
                                             const float* __restrict__ a1s,
                                             const float* __restrict__ a1d,
                                             const float* __restrict__ gb1,
                                             unsigned int* __restrict__ out1u, int N) {
    int tid = threadIdx.x, lane = tid & 63;
    int n0 = blockIdx.x * 4 + (tid >> 6);
    int n  = __builtin_amdgcn_readfirstlane(n0 < N ? n0 : N - 1);

    int start = rowptr[n], end = rowptr[n + 1];
    int q = lane >> 4, c = lane & 15;     // stream q; channels 8c..8c+7
    int hsel = c >> 2;                    // head
    float advh = a1d[n * 4 + hsel];
    const uint4* h1q = reinterpret_cast<const uint4*>(h1u);

    float den = 0.f;
    float a0 = 0.f, a1v = 0.f, a2v = 0.f, a3v = 0.f;
    float a4 = 0.f, a5 = 0.f, a6 = 0.f, a7 = 0.f;
    if (q == 0) {                         // self loop on stream 0
        float w = __expf(lrelu(a1s[n * 4 + hsel] + advh));
        uint4 u = h1q[(size_t)n * 16 + c];
        den = w;
        a0 = w * bf_lo(u.x); a1v = w * bf_hi(u.x);
        a2v = w * bf_lo(u.y); a3v = w * bf_hi(u.y);
        a4 = w * bf_lo(u.z); a5 = w * bf_hi(u.z);
        a6 = w * bf_lo(u.w); a7 = w * bf_hi(u.w);
    }
    int e = start + q;
    for (; e + 4 < end; e += 8) {         // 2-edge unroll per stream
        int s0 = col[e], s1 = col[e + 4];
        float q0 = a1s[s0 * 4 + hsel];
        float q1 = a1s[s1 * 4 + hsel];
        uint4 u0 = h1q[(size_t)s0 * 16 + c];
        uint4 u1 = h1q[(size_t)s1 * 16 + c];
        float w0 = __expf(lrelu(q0 + advh));
        float w1 = __expf(lrelu(q1 + advh));
        den += w0 + w1;
        a0 = fmaf(w0, bf_lo(u0.x), a0); a1v = fmaf(w0, bf_hi(u0.x), a1v);
        a2v = fmaf(w0, bf_lo(u0.y), a2v); a3v = fmaf(w0, bf_hi(u0.y), a3v);
        a4 = fmaf(w0, bf_lo(u0.z), a4); a5 = fmaf(w0, bf_hi(u0.z), a5);
        a6 = fmaf(w0, bf_lo(u0.w), a6); a7 = fmaf(w0, bf_hi(u0.w), a7);
        a0 = fmaf(w1, bf_lo(u1.x), a0); a1v = fmaf(w1, bf_hi(u1.x), a1v);
        a2v = fmaf(w1, bf_lo(u1.y), a2v); a3v = fmaf(w1, bf_hi(u1.y), a3v);
        a4 = fmaf(w1, bf_lo(u1.z), a4); a5 = fmaf(w1, bf_hi(u1.z), a5);
        a6 = fmaf(w1, bf_lo(u1.w), a6); a7 = fmaf(w1, bf_hi(u1.w), a7);
    }
    if (e < end) {
        int s = col[e];
        float qv = a1s[s * 4 + hsel];
        uint4 u = h1q[(size_t)s * 16 + c];
        float w = __expf(lrelu(qv + advh));
        den += w;
        a0 = fmaf(w, bf_lo(u.x), a0); a1v = fmaf(w, bf_hi(u.x), a1v);
        a2v = fmaf(w, bf_lo(u.y), a2v); a3v = fmaf(w, bf_hi(u.y), a3v);
        a4 = fmaf(w, bf_lo(u.z), a4); a5 = fmaf(w, bf_hi(u.z), a5);
        a6 = fmaf(w, bf_lo(u.w), a6); a7 = fmaf(w, bf_hi(u.w), a7);
    }
#define RED2(v) v += __shfl_xor(v, 16); v += __shfl_xor(v, 32);
    RED2(den) RED2(a0) RED2(a1v) RED2(a2v) RED2(a3v)
    RED2(a4) RED2(a5) RED2(a6) RED2(a7)
#undef RED2

    if (n0 < N && lane < 16) {
        float inv = 1.f / den;
        float v0 = a0 * inv + gb1[8 * c + 0];
        float v1 = a1v * inv + gb1[8 * c + 1];
        float v2 = a2v * inv + gb1[8 * c + 2];
        float v3 = a3v * inv + gb1[8 * c + 3];
        float v4 = a4 * inv + gb1[8 * c + 4];
        float v5 = a5 * inv + gb1[8 * c + 5];
        float v6 = a6 * inv + gb1[8 * c + 6];
        float v7 = a7 * inv + gb1[8 * c + 7];
        v0 = (v0 > 0.f) ? v0 : (__expf(v0) - 1.f);
        v1 = (v1 > 0.f) ? v1 : (__expf(v1) - 1.f);
        v2 = (v2 > 0.f) ? v2 : (__expf(v2) - 1.f);
        v3 = (v3 > 0.f) ? v3 : (__expf(v3) - 1.f);
        v4 = (v4 > 0.f) ? v4 : (__expf(v4) - 1.f);
        v5 = (v5 > 0.f) ? v5 : (__expf(v5) - 1.f);
        v6 = (v6 > 0.f) ? v6 : (__expf(v6) - 1.f);
        v7 = (v7 > 0.f) ? v7 : (__expf(v7) - 1.f);
        uint4 o;
        o.x = pack_bf16(v0, v1); o.y = pack_bf16(v2, v3);
        o.z = pack_bf16(v4, v5); o.w = pack_bf16(v6, v7);
        *reinterpret_cast<uint4*>(out1u + (size_t)n * 64 + 4 * c) = o;
    }
}

// ---------------------------------------------------------------------------
// GATConv2 projection via MFMA: h2 = out1 @ gW2 (bf16 in/out) + scores.
// ---------------------------------------------------------------------------
__global__ __launch_bounds__(256) void k_g2a(const unsigned short* __restrict__ out1b,
                                             const float* __restrict__ gW2,
                                             const float* __restrict__ a2sw,
                                             const float* __restrict__ a2dw,
                                             unsigned short* __restrict__ h2b,
                                             float* __restrict__ a2s,
                                             float* __restrict__ a2d, int N) {
    int lane = threadIdx.x & 63;
    int wid  = (blockIdx.x * blockDim.x + threadIdx.x) >> 6;
    int nwav = (gridDim.x * blockDim.x) >> 6;
    int col = lane & 15, g4 = lane >> 4;

    short8v Bf[4][4];
#pragma unroll
    for (int ks = 0; ks < 4; ++ks)
#pragma unroll
        for (int cb = 0; cb < 4; ++cb) {
            union { short8v v; unsigned short u[8]; } bu;
#pragma unroll
            for (int j = 0; j < 8; ++j)
                bu.u[j] = f2bf_rne(gW2[(ks * 32 + g4 * 8 + j) * 64 + cb * 16 + col]);
            Bf[ks][cb] = bu.v;
        }
    float asv[4], adv[4];
#pragma unroll
    for (int cb = 0; cb < 4; ++cb) { asv[cb] = a2sw[cb * 16 + col]; adv[cb] = a2dw[cb * 16 + col]; }

    int ntile = (N + 15) >> 4;
    for (int t = wid; t < ntile; t += nwav) {
        int n0 = t * 16;
        int node = n0 + col; if (node >= N) node = N - 1;
        const unsigned short* xr = out1b + (size_t)node * 128;
        f32x4 acc0 = {0.f, 0.f, 0.f, 0.f}, acc1 = acc0, acc2 = acc0, acc3 = acc0;
#pragma unroll
        for (int ks = 0; ks < 4; ++ks) {
            short8v a = *reinterpret_cast<const short8v*>(xr + ks * 32 + g4 * 8);
            acc0 = __builtin_amdgcn_mfma_f32_16x16x32_bf16(a, Bf[ks][0], acc0, 0, 0, 0);
            acc1 = __builtin_amdgcn_mfma_f32_16x16x32_bf16(a, Bf[ks][1], acc1, 0, 0, 0);
            acc2 = __builtin_amdgcn_mfma_f32_16x16x32_bf16(a, Bf[ks][2], acc2, 0, 0, 0);
            acc3 = __builtin_amdgcn_mfma_f32_16x16x32_bf16(a, Bf[ks][3], acc3, 0, 0, 0);
        }
        float ps[4] = {0.f, 0.f, 0.f, 0.f}, pd[4] = {0.f, 0.f, 0.f, 0.f};
#define G2A_EPI(CB, ACC)                                                      \
        {                                                                     \
            _Pragma("unroll")                                                 \
            for (int i = 0; i < 4; ++i) {                                     \
                float v = ACC[i];                                             \
                int r = n0 + g4 * 4 + i;                                      \
                if (r < N) h2b[(size_t)r * 64 + CB * 16 + col] = f2bf_rne(v); \
                ps[i] = fmaf(v, asv[CB], ps[i]);                              \
                pd[i] = fmaf(v, adv[CB], pd[i]);                              \
            }                                                                 \
        }
        G2A_EPI(0, acc0) G2A_EPI(1, acc1) G2A_EPI(2, acc2) G2A_EPI(3, acc3)
#undef G2A_EPI
#pragma unroll
        for (int i = 0; i < 4; ++i) {
            ps[i] += __shfl_xor(ps[i], 1); ps[i] += __shfl_xor(ps[i], 2);
            ps[i] += __shfl_xor(ps[i], 4); ps[i] += __shfl_xor(ps[i], 8);
            pd[i] += __shfl_xor(pd[i], 1); pd[i] += __shfl_xor(pd[i], 2);
            pd[i] += __shfl_xor(pd[i], 4); pd[i] += __shfl_xor(pd[i], 8);
        }
        if (col == 0) {
#pragma unroll
            for (int i = 0; i < 4; ++i) {
                int r = n0 + g4 * 4 + i;
                if (r < N) { a2s[r] = ps[i]; a2d[r] = pd[i]; }
            }
        }
    }
}

// ---------------------------------------------------------------------------
// GATConv2 aggregation. Eighth-wave per edge stream (8 streams x 8 lanes),
// 8 ch/lane via uint4. Chain ~deg/8; combine shfl_xor(8,16,32).
// ---------------------------------------------------------------------------
__global__ __launch_bounds__(256) void k_g2b(const int* __restrict__ rowptr,
                                             const int* __restrict__ col,
                                             const unsigned int* __restrict__ h2u,
                                             const float* __restrict__ a2s,
                                             const float* __restrict__ a2d,
                                             const float* __restrict__ gb2,
                                             unsigned int* __restrict__ gu, int N) {
    int tid = threadIdx.x, lane = tid & 63;
    int n0 = blockIdx.x * 4 + (tid >> 6);
    int n  = __builtin_amdgcn_readfirstlane(n0 < N ? n0 : N - 1);

    int start = rowptr[n], end = rowptr[n + 1];
    int q = lane >> 3, c = lane & 7;     // stream q; channels 8c..8c+7
    float ad = a2d[n];
    const uint4* h2q = reinterpret_cast<const uint4*>(h2u);

    float den = 0.f;
    float a0 = 0.f, a1v = 0.f, a2v = 0.f, a3v = 0.f;
    float a4 = 0.f, a5 = 0.f, a6 = 0.f, a7 = 0.f;
    if (q == 0) {                        // self loop on stream 0
        float w = __expf(lrelu(a2s[n] + ad));
        uint4 u = h2q[(size_t)n * 8 + c];
        den = w;
        a0 = w * bf_lo(u.x); a1v = w * bf_hi(u.x);
        a2v = w * bf_lo(u.y); a3v = w * bf_hi(u.y);
        a4 = w * bf_lo(u.z); a5 = w * bf_hi(u.z);
        a6 = w * bf_lo(u.w); a7 = w * bf_hi(u.w);
    }
    for (int e = start + q; e < end; e += 8) {
        int s = col[e];
        float w = __expf(lrelu(a2s[s] + ad));
        uint4 u = h2q[(size_t)s * 8 + c];
        den += w;
        a0 = fmaf(w, bf_lo(u.x), a0); a1v = fmaf(w, bf_hi(u.x), a1v);
        a2v = fmaf(w, bf_lo(u.y), a2v); a3v = fmaf(w, bf_hi(u.y), a3v);
        a4 = fmaf(w, bf_lo(u.z), a4); a5 = fmaf(w, bf_hi(u.z), a5);
        a6 = fmaf(w, bf_lo(u.w), a6); a7 = fmaf(w, bf_hi(u.w), a7);
    }
#define RED3(v) v += __shfl_xor(v, 8); v += __shfl_xor(v, 16); v += __shfl_xor(v, 32);
    RED3(den) RED3(a0) RED3(a1v) RED3(a2v) RED3(a3v)
    RED3(a4) RED3(a5) RED3(a6) RED3(a7)
#undef RED3

    if (n0 < N && lane < 8) {
        float inv = 1.f / den;
        uint4 o;
        o.x = pack_bf16(a0 * inv + gb2[8 * c + 0], a1v * inv + gb2[8 * c + 1]);
        o.y = pack_bf16(a2v * inv + gb2[8 * c + 2], a3v * inv + gb2[8 * c + 3]);
        o.z = pack_bf16(a4 * inv + gb2[8 * c + 4], a5 * inv + gb2[8 * c + 5]);
        o.w = pack_bf16(a6 * inv + gb2[8 * c + 6], a7 * inv + gb2[8 * c + 7]);
        *reinterpret_cast<uint4*>(gu + (size_t)n * 32 + 4 * c) = o;
    }
}

// ---------------------------------------------------------------------------
// Classifier via MFMA: sigmoid(relu([m,g] @ Wf + bc) @ cW2 + cb2)
// ---------------------------------------------------------------------------
__global__ __launch_bounds__(256) void k_cls(const unsigned short* __restrict__ mb,
                                             const unsigned short* __restrict__ gb,
                                             const unsigned short* __restrict__ Wf,
                                             const float* __restrict__ bc,
                                             const float* __restrict__ cW2,
                                             const float* __restrict__ cb2,
                                             float* __restrict__ out, int N) {
    int lane = threadIdx.x & 63;
    int wid  = (blockIdx.x * blockDim.x + threadIdx.x) >> 6;
    int nwav = (gridDim.x * blockDim.x) >> 6;
    int col = lane & 15, g4 = lane >> 4;

    short8v Bf[4][4];
#pragma unroll
    for (int ks = 0; ks < 4; ++ks)
#pragma unroll
        for (int cb = 0; cb < 4; ++cb) {
            union { short8v v; unsigned short u[8]; } bu;
#pragma unroll
            for (int j = 0; j < 8; ++j)
                bu.u[j] = Wf[(ks * 32 + g4 * 8 + j) * 64 + cb * 16 + col];
            Bf[ks][cb] = bu.v;
        }
    float w2v[4], bcv[4];
#pragma unroll
    for (int cb = 0; cb < 4; ++cb) { w2v[cb] = cW2[cb * 16 + col]; bcv[cb] = bc[cb * 16 + col]; }
    float cb2v = cb2[0];

    int ntile = (N + 15) >> 4;
    for (int t = wid; t < ntile; t += nwav) {
        int n0 = t * 16;
        int node = n0 + col; if (node >= N) node = N - 1;
        const unsigned short* mr = mb + (size_t)node * 64;
        const unsigned short* gr = gb + (size_t)node * 64;
        f32x4 acc0 = {0.f, 0.f, 0.f, 0.f}, acc1 = acc0, acc2 = acc0, acc3 = acc0;
#pragma unroll
        for (int ks = 0; ks < 4; ++ks) {
            short8v a = (ks < 2)
                ? *reinterpret_cast<const short8v*>(mr + ks * 32 + g4 * 8)
                : *reinterpret_cast<const short8v*>(gr + (ks - 2) * 32 + g4 * 8);
            acc0 = __builtin_amdgcn_mfma_f32_16x16x32_bf16(a, Bf[ks][0], acc0, 0, 0, 0);
            acc1 = __builtin_amdgcn_mfma_f32_16x16x32_bf16(a, Bf[ks][1], acc1, 0, 0, 0);
            acc2 = __builtin_amdgcn_mfma_f32_16x16x32_bf16(a, Bf[ks][2], acc2, 0, 0, 0);
            acc3 = __builtin_amdgcn_mfma_f32_16x16x32_bf16(a, Bf[ks][3], acc3, 0, 0, 0);
        }
        float z[4] = {0.f, 0.f, 0.f, 0.f};
#define CLS_EPI(CB, ACC)                                                   \
        {                                                                  \
            _Pragma("unroll")                                              \
            for (int i = 0; i < 4; ++i)                                    \
                z[i] = fmaf(fmaxf(ACC[i] + bcv[CB], 0.f), w2v[CB], z[i]);  \
        }
        CLS_EPI(0, acc0) CLS_EPI(1, acc1) CLS_EPI(2, acc2) CLS_EPI(3, acc3)
#undef CLS_EPI
#pragma unroll
        for (int i = 0; i < 4; ++i) {
            z[i] += __shfl_xor(z[i], 1); z[i] += __shfl_xor(z[i], 2);
            z[i] += __shfl_xor(z[i], 4); z[i] += __shfl_xor(z[i], 8);
        }
        if (col == 0) {
#pragma unroll
            for (int i = 0; i < 4; ++i) {
                int r = n0 + g4 * 4 + i;
                if (r < N) out[r] = 1.f / (1.f + __expf(-(z[i] + cb2v)));
            }
        }
    }
}

// ---------------------------------------------------------------------------
extern "C" void kernel_launch(void* const* d_in, const int* in_sizes, int n_in,
                              void* d_out, int out_size, void* d_ws, size_t ws_size,
                              hipStream_t stream) {
    const float* td   = (const float*)d_in[0];
    const float* x    = (const float*)d_in[1];
    const int*   ei   = (const int*)d_in[2];
    const float* tW1  = (const float*)d_in[3];
    const float* tb1  = (const float*)d_in[4];
    const float* tW2  = (const float*)d_in[5];
    const float* tb2  = (const float*)d_in[6];
    const float* gW1  = (const float*)d_in[7];
    const float* ga1s = (const float*)d_in[8];
    const float* ga1d = (const float*)d_in[9];
    const float* gb1  = (const float*)d_in[10];
    const float* gW2  = (const float*)d_in[11];
    const float* ga2s = (const float*)d_in[12];
    const float* ga2d = (const float*)d_in[13];
    const float* gb2  = (const float*)d_in[14];
    const float* cW1  = (const float*)d_in[15];
    const float* cb1  = (const float*)d_in[16];
    const float* cW2  = (const float*)d_in[17];
    const float* cb2  = (const float*)d_in[18];

    int N = in_sizes[1] / 10;
    int E = in_sizes[2] / 2;

    float* fws = (float*)d_ws;
    unsigned short* mb16   = (unsigned short*)fws;                    // [N,64] bf16
    unsigned short* h1b    = (unsigned short*)(fws + (size_t)N * 32); // [N,128] bf16
    unsigned short* out1b  = (unsigned short*)(fws + (size_t)N * 96); // [N,128] bf16
    float* a1s   = fws + (size_t)N * 160;
    float* a1d   = fws + (size_t)N * 164;
    unsigned short* h2b = h1b;       // reuse (h1 dead after k_g1b)  [N,64] bf16
    float* a2s   = a1s;              // reuse
    float* a2d   = a1d;              // reuse
    unsigned short* gb16 = out1b;    // reuse (out1 dead after k_g2a) [N,64] bf16

    int* ib       = (int*)(fws + (size_t)N * 168);
    int* counts   = ib;
    int* rowptr   = ib + N;
    int* nxt      = ib + 2 * N + 1;
    int* partials = ib + 3 * N + 1;
    int* col      = ib + 3 * N + 1 + 128;

    unsigned short* Wf = (unsigned short*)(col + E);
    float* bcf = (float*)(Wf + 8192);

    int NB = (N + 1023) / 1024;
    int range = (N + SC_P - 1) / SC_P;
    int nb4   = (N + 3) / 4;
    int ntile = (N + 15) / 16;
    int nbt   = (ntile + 3) / 4;

    k_zero<<<256, 256, 0, stream>>>(counts, N);

    k_temporal<<<2048, 256, 0, stream>>>(td, tW1, tb1, ei, counts,
                                         tW2, cW1, tb2, cb1, Wf, bcf, mb16, N, E);
    k_scan1  <<<NB, 1024, 0, stream>>>(counts, rowptr, partials, N);
    k_scan3  <<<(N + 1 + 255) / 256, 256, 0, stream>>>(rowptr, partials, nxt, N);
    k_scatter<<<(E + 256 * SC_K - 1) / (256 * SC_K), 256, 0, stream>>>(ei, nxt, col, E, range);

    k_g1a<<<nb4, 256, 0, stream>>>(x, gW1, ga1s, ga1d, h1b, a1s, a1d, N);
    k_g1b<<<nb4, 256, 0, stream>>>(rowptr, col, (const unsigned int*)h1b, a1s, a1d, gb1,
                                   (unsigned int*)out1b, N);
    k_g2a<<<nbt, 256, 0, stream>>>(out1b, gW2, ga2s, ga2d, h2b, a2s, a2d, N);
    k_g2b<<<nb4, 256, 0, stream>>>(rowptr, col, (const unsigned int*)h2b, a2s, a2d, gb2,
                                   (unsigned int*)gb16, N);
    k_cls<<<nbt, 256, 0, stream>>>(mb16, gb16, Wf, bcf, cW2, cb2, (float*)d_out, N);
}

// Round 18
// 373.057 us; speedup vs baseline: 1.1176x; 1.0526x over previous
//
#include <hip/hip_runtime.h>
#include <hip/hip_bf16.h>

#define DEV_INLINE __device__ __forceinline__

typedef __attribute__((ext_vector_type(8))) short short8v;
typedef __attribute__((ext_vector_type(4))) float f32x4;

DEV_INLINE float lrelu(float v) { return fmaxf(v, 0.2f * v); }

DEV_INLINE unsigned int cvt_pk_bf16(float lo, float hi) {
    unsigned int r;
    asm("v_cvt_pk_bf16_f32 %0, %1, %2" : "=v"(r) : "v"(lo), "v"(hi));
    return r;
}

DEV_INLINE unsigned short f2bf_rne(float f) {
    unsigned int b = __float_as_uint(f);
    return (unsigned short)((b + 0x7FFFu + ((b >> 16) & 1u)) >> 16);
}

DEV_INLINE unsigned int pack_bf16(float lo, float hi) {
    return (unsigned int)f2bf_rne(lo) | ((unsigned int)f2bf_rne(hi) << 16);
}

DEV_INLINE float bf_lo(unsigned int u) { return __uint_as_float(u << 16); }
DEV_INLINE float bf_hi(unsigned int u) { return __uint_as_float(u & 0xFFFF0000u); }

// ---------------------------------------------------------------------------
__global__ void k_zero(int* __restrict__ p, int n) {
    int i = blockIdx.x * blockDim.x + threadIdx.x;
    int stride = gridDim.x * blockDim.x;
    for (; i < n; i += stride) p[i] = 0;
}

// ---------------------------------------------------------------------------
// CSR scan kernels
// ---------------------------------------------------------------------------
__global__ __launch_bounds__(1024) void k_scan1(const int* __restrict__ counts,
                                                int* __restrict__ rowptr,
                                                int* __restrict__ partials, int N) {
    __shared__ int sd[1024];
    int li = threadIdx.x;
    int i  = blockIdx.x * 1024 + li;
    int v  = (i < N) ? counts[i] : 0;
    sd[li] = v;
    __syncthreads();
    for (int off = 1; off < 1024; off <<= 1) {
        int t = (li >= off) ? sd[li - off] : 0;
        __syncthreads();
        sd[li] += t;
        __syncthreads();
    }
    int inc = sd[li];
    if (i < N) rowptr[i + 1] = inc;
    if (li == 1023) partials[blockIdx.x] = inc;   // raw chunk totals
}

__global__ void k_scan3(int* __restrict__ rowptr, const int* __restrict__ partials,
                        int* __restrict__ nxt, int N) {
    int i = blockIdx.x * blockDim.x + threadIdx.x;
    if (i > N) return;
    int v;
    if (i == 0) { v = 0; rowptr[0] = 0; }
    else {
        int blk = (i - 1) >> 10;
        int pp = 0;
        for (int b = 0; b < blk; ++b) pp += partials[b];
        v = rowptr[i] + pp;
        rowptr[i] = v;
    }
    if (i < N) nxt[i] = v;
}

#define SC_K 8
#define SC_P 16
__global__ __launch_bounds__(256) void k_scatter(const int* __restrict__ ei,
                                                 int* __restrict__ nxt,
                                                 int* __restrict__ col,
                                                 int E, int range) {
    int t = threadIdx.x;
    int base = blockIdx.x * (256 * SC_K);
    int s[SC_K], d[SC_K];
#pragma unroll
    for (int k = 0; k < SC_K; ++k) {
        int e = base + k * 256 + t;
        bool v = (e < E);
        s[k] = v ? ei[e] : 0;
        d[k] = v ? ei[E + e] : -1;
    }
    int lo = 0;
    for (int p = 0; p < SC_P; ++p, lo += range) {
        int hi = lo + range;
#pragma unroll
        for (int k = 0; k < SC_K; ++k) {
            if (d[k] >= lo && d[k] < hi) {
                int pos = atomicAdd(&nxt[d[k]], 1);
                col[pos] = s[k];
            }
        }
        __syncthreads();
    }
}

// ---------------------------------------------------------------------------
// Per-node temporal compute from an LDS slot (512 floats). 3 MFMA tiles cover
// t=0..47; t=48,49 as fp32 VALU tail with lane=channel weights.
// ---------------------------------------------------------------------------
DEV_INLINE void temporal_node(const float* wb, int col, int g, const short8v* B,
                              const float* w1c, float b1c,
                              int lane, unsigned short* mb, size_t n) {
    float sum0 = 0.f, sum1 = 0.f, sum2 = 0.f, sum3 = 0.f;
#pragma unroll
    for (int tt = 0; tt < 3; ++tt) {
        int t = tt * 16 + col;
        float x0 = 0.f, x1 = 0.f, x2 = 0.f, x3 = 0.f;
        float x4 = 0.f, x5 = 0.f, x6 = 0.f, x7 = 0.f;
        const float* rp = wb + t * 10;
        if (g == 0) {
            float2 p0 = *reinterpret_cast<const float2*>(rp);
            float2 p1 = *reinterpret_cast<const float2*>(rp + 2);
            float2 p2 = *reinterpret_cast<const float2*>(rp + 4);
            float2 p3 = *reinterpret_cast<const float2*>(rp + 6);
            x0 = p0.x; x1 = p0.y; x2 = p1.x; x3 = p1.y;
            x4 = p2.x; x5 = p2.y; x6 = p3.x; x7 = p3.y;
        } else if (g == 1) {
            float2 p4 = *reinterpret_cast<const float2*>(rp + 8);
            x0 = p4.x; x1 = p4.y; x2 = 1.0f;
        }
        union { short8v v; unsigned int w[4]; } au;
        au.w[0] = cvt_pk_bf16(x0, x1);
        au.w[1] = cvt_pk_bf16(x2, x3);
        au.w[2] = cvt_pk_bf16(x4, x5);
        au.w[3] = cvt_pk_bf16(x6, x7);

        f32x4 z = {0.f, 0.f, 0.f, 0.f};
        f32x4 c0 = __builtin_amdgcn_mfma_f32_16x16x32_bf16(au.v, B[0], z, 0, 0, 0);
        f32x4 c1 = __builtin_amdgcn_mfma_f32_16x16x32_bf16(au.v, B[1], z, 0, 0, 0);
        f32x4 c2 = __builtin_amdgcn_mfma_f32_16x16x32_bf16(au.v, B[2], z, 0, 0, 0);
        f32x4 c3 = __builtin_amdgcn_mfma_f32_16x16x32_bf16(au.v, B[3], z, 0, 0, 0);
#pragma unroll
        for (int i = 0; i < 4; ++i) {
            sum0 += fmaxf(c0[i], 0.f);
            sum1 += fmaxf(c1[i], 0.f);
            sum2 += fmaxf(c2[i], 0.f);
            sum3 += fmaxf(c3[i], 0.f);
        }
    }
    sum0 += __shfl_xor(sum0, 16); sum0 += __shfl_xor(sum0, 32);
    sum1 += __shfl_xor(sum1, 16); sum1 += __shfl_xor(sum1, 32);
    sum2 += __shfl_xor(sum2, 16); sum2 += __shfl_xor(sum2, 32);
    sum3 += __shfl_xor(sum3, 16); sum3 += __shfl_xor(sum3, 32);
    float mv = (g == 0) ? sum0 : (g == 1) ? sum1 : (g == 2) ? sum2 : sum3;

    const float* tp = wb + 480;
    float u48 = b1c, u49 = b1c;
#pragma unroll
    for (int i = 0; i < 10; ++i) {
        u48 = fmaf(tp[i],      w1c[i], u48);
        u49 = fmaf(tp[10 + i], w1c[i], u49);
    }
    mv += fmaxf(u48, 0.f) + fmaxf(u49, 0.f);

    mb[n * 64 + lane] = f2bf_rne(mv * 0.02f);
}

// ---------------------------------------------------------------------------
// Temporal encoder (+ folded edge-count histogram + classifier-weight fuse).
// Static double buffer, 2-node unrolled loop, distance-2 register staging.
// Grid 4096 (16384 waves, ~6 nodes/wave) for more latency-hiding TLP.
// ---------------------------------------------------------------------------
__global__ __launch_bounds__(256) void k_temporal(const float* __restrict__ td,
                                                  const float* __restrict__ tW1,
                                                  const float* __restrict__ tb1,
                                                  const int* __restrict__ ei,
                                                  int* __restrict__ counts,
                                                  const float* __restrict__ tW2,
                                                  const float* __restrict__ cW1,
                                                  const float* __restrict__ tb2,
                                                  const float* __restrict__ cb1,
                                                  unsigned short* __restrict__ Wf,
                                                  float* __restrict__ bcf,
                                                  unsigned short* __restrict__ mb,
                                                  int N, int E) {
    __shared__ float b0lds[4][512];
    __shared__ float b1lds[4][512];
    int tid = threadIdx.x, lane = tid & 63, wv = tid >> 6;
    int gid = blockIdx.x * 256 + tid;

    // ---- folded k_count ----
    int estr = gridDim.x * 256;
    for (int e = gid; e < E; e += estr) atomicAdd(&counts[ei[E + e]], 1);

    // ---- folded k_fuse ----
    if (gid < 4096) {
        int i = gid >> 6, c = gid & 63;
        float s = 0.f;
#pragma unroll 8
        for (int k = 0; k < 64; ++k) s = fmaf(tW2[i * 64 + k], cW1[k * 64 + c], s);
        Wf[gid] = f2bf_rne(s);
    } else if (gid < 8192) {
        Wf[gid] = f2bf_rne(cW1[gid]);
    } else if (gid < 8256) {
        int c = gid - 8192;
        float s = cb1[c];
#pragma unroll 8
        for (int k = 0; k < 64; ++k) s = fmaf(tb2[k], cW1[k * 64 + c], s);
        bcf[c] = s;
    }

    int wid  = gid >> 6;
    int nwav = (gridDim.x * 256) >> 6;
    int col  = lane & 15;
    int g    = lane >> 4;

    int chunk = (N + nwav - 1) / nwav;
    int n0 = wid * chunk;
    int n1 = min(n0 + chunk, N);
    if (n0 >= n1) return;
    int cnt = n1 - n0;

    short8v B[4];
#pragma unroll
    for (int cb = 0; cb < 4; ++cb) {
        union { short8v v; unsigned short u[8]; } bu;
#pragma unroll
        for (int j = 0; j < 8; ++j) {
            int f = g * 8 + j;
            int c = cb * 16 + col;
            float w = (f < 10) ? tW1[f * 64 + c] : ((f == 10) ? tb1[c] : 0.f);
            bu.u[j] = f2bf_rne(w);
        }
        B[cb] = bu.v;
    }
    float w1c[10];
#pragma unroll
    for (int i = 0; i < 10; ++i) w1c[i] = tW1[i * 64 + lane];
    float b1c = tb1[lane];

    float* buf0 = &b0lds[wv][0];
    float* buf1 = &b1lds[wv][0];
    float4 zero4 = make_float4(0.f, 0.f, 0.f, 0.f);

#define LOADROW(J, A, Bv)                                                      \
    {                                                                          \
        int nn = n0 + (J); if (nn > n1 - 1) nn = n1 - 1;                       \
        const float4* rr = reinterpret_cast<const float4*>(td + (size_t)nn * 500); \
        A = rr[lane];                                                          \
        Bv = (lane < 61) ? rr[64 + lane] : zero4;                              \
    }
#define WRITEBUF(BUF, A, Bv)                                                   \
    {                                                                          \
        *reinterpret_cast<float4*>((BUF) + 4 * lane) = A;                      \
        if (lane < 61) *reinterpret_cast<float4*>((BUF) + 256 + 4 * lane) = Bv;\
    }

    float4 aA, bA, aB, bB;
    LOADROW(0, aA, bA)
    LOADROW(1, aB, bB)
    WRITEBUF(buf0, aA, bA)
    LOADROW(2, aA, bA)
    WRITEBUF(buf1, aB, bB)
    LOADROW(3, aB, bB)

    int i = 0;
    for (; i + 1 < cnt; i += 2) {
        temporal_node(buf0, col, g, B, w1c, b1c, lane, mb, (size_t)(n0 + i));
        WRITEBUF(buf0, aA, bA)
        LOADROW(i + 4, aA, bA)
        temporal_node(buf1, col, g, B, w1c, b1c, lane, mb, (size_t)(n0 + i + 1));
        WRITEBUF(buf1, aB, bB)
        LOADROW(i + 5, aB, bB)
    }
    if (i < cnt)
        temporal_node(buf0, col, g, B, w1c, b1c, lane, mb, (size_t)(n0 + i));
#undef LOADROW
#undef WRITEBUF
}

// ---------------------------------------------------------------------------
// GATConv1 projection + attention scores. h1b bf16 [n,128], a1s/a1d fp32 [n,4]
// ---------------------------------------------------------------------------
__global__ __launch_bounds__(256) void k_g1a(const float* __restrict__ x,
                                             const float* __restrict__ gW1,
                                             const float* __restrict__ as_w,
                                             const float* __restrict__ ad_w,
                                             unsigned short* __restrict__ h1b,
                                             float* __restrict__ a1s,
                                             float* __restrict__ a1d, int N) {
    int tid = threadIdx.x, lane = tid & 63;
    int n0 = blockIdx.x * 4 + (tid >> 6);
    int n  = __builtin_amdgcn_readfirstlane(n0 < N ? n0 : N - 1);

    float wa[10], wb[10];
#pragma unroll
    for (int i = 0; i < 10; ++i) { wa[i] = gW1[i * 128 + lane]; wb[i] = gW1[i * 128 + 64 + lane]; }
    const float* xp = x + (size_t)n * 10;
    float ha = 0.f, hb = 0.f;
#pragma unroll
    for (int i = 0; i < 10; ++i) { float xv = xp[i]; ha = fmaf(xv, wa[i], ha); hb = fmaf(xv, wb[i], hb); }

    int c = lane & 31;
    int headA = lane >> 5;
    float ps_a = ha * as_w[headA * 32 + c];
    float ps_b = hb * as_w[(headA + 2) * 32 + c];
    float pd_a = ha * ad_w[headA * 32 + c];
    float pd_b = hb * ad_w[(headA + 2) * 32 + c];
#pragma unroll
    for (int m = 1; m < 32; m <<= 1) {
        ps_a += __shfl_xor(ps_a, m); ps_b += __shfl_xor(ps_b, m);
        pd_a += __shfl_xor(pd_a, m); pd_b += __shfl_xor(pd_b, m);
    }
    if (n0 < N) {
        h1b[(size_t)n * 128 + lane]      = f2bf_rne(ha);
        h1b[(size_t)n * 128 + 64 + lane] = f2bf_rne(hb);
        if (c == 0) {
            a1s[n * 4 + headA]     = ps_a;
            a1s[n * 4 + 2 + headA] = ps_b;
            a1d[n * 4 + headA]     = pd_a;
            a1d[n * 4 + 2 + headA] = pd_b;
        }
    }
}

// ---------------------------------------------------------------------------
// GATConv1 aggregation. Quarter-wave per edge stream; index-ahead pipelining:
// next iteration's col indices load before current gathers are consumed.
// ---------------------------------------------------------------------------
__global__ __launch_bounds__(256) void k_g1b(const int* __restrict__ rowptr,
                                             const int* __restrict__ col,
                                             const unsigned int* __restrict__ h1u,
                                             const float* __restrict__ a1s,
                                             const float* __restrict__ a1d,
                                             const float* __restrict__ gb1,
                                             unsigned int* __restrict__ out1u, int N) {
    int tid = threadIdx.x, lane = tid & 63;
    int n0 = blockIdx.x * 4 + (tid >> 6);
    int n  = __builtin_amdgcn_readfirstlane(n0 < N ? n0 : N - 1);

    int start = rowptr[n], end = rowptr[n + 1];
    int q = lane >> 4, c = lane & 15;     // stream q; channels 8c..8c+7
    int hsel = c >> 2;                    // head
    float advh = a1d[n * 4 + hsel];
    const uint4* h1q = reinterpret_cast<const uint4*>(h1u);

    float den = 0.f;
    float a0 = 0.f, a1v = 0.f, a2v = 0.f, a3v = 0.f;
    float a4 = 0.f, a5 = 0.f, a6 = 0.f, a7 = 0.f;
    if (q == 0) {                         // self loop on stream 0
        float w = __expf(lrelu(a1s[n * 4 + hsel] + advh));
        uint4 u = h1q[(size_t)n * 16 + c];
        den = w;
        a0 = w * bf_lo(u.x); a1v = w * bf_hi(u.x);
        a2v = w * bf_lo(u.y); a3v = w * bf_hi(u.y);
        a4 = w * bf_lo(u.z); a5 = w * bf_hi(u.z);
        a6 = w * bf_lo(u.w); a7 = w * bf_hi(u.w);
    }
    int e = start + q;
    int s0 = 0, s1 = 0;
    bool have2 = (e + 4 < end);
    if (have2) { s0 = col[e]; s1 = col[e + 4]; }
    for (; e + 4 < end; ) {
        int cs0 = s0, cs1 = s1;
        e += 8;
        if (e + 4 < end) { s0 = col[e]; s1 = col[e + 4]; }   // index-ahead
        float q0 = a1s[cs0 * 4 + hsel];
        float q1 = a1s[cs1 * 4 + hsel];
        uint4 u0 = h1q[(size_t)cs0 * 16 + c];
        uint4 u1 = h1q[(size_t)cs1 * 16 + c];
        float w0 = __expf(lrelu(q0 + advh));
        float w1 = __expf(lrelu(q1 + advh));
        den += w0 + w1;
        a0 = fmaf(w0, bf_lo(u0.x), a0); a1v = fmaf(w0, bf_hi(u0.x), a1v);
        a2v = fmaf(w0, bf_lo(u0.y), a2v); a3v = fmaf(w0, bf_hi(u0.y), a3v);
        a4 = fmaf(w0, bf_lo(u0.z), a4); a5 = fmaf(w0, bf_hi(u0.z), a5);
        a6 = fmaf(w0, bf_lo(u0.w), a6); a7 = fmaf(w0, bf_hi(u0.w), a7);
        a0 = fmaf(w1, bf_lo(u1.x), a0); a1v = fmaf(w1, bf_hi(u1.x), a1v);
        a2v = fmaf(w1, bf_lo(u1.y), a2v); a3v = fmaf(w1, bf_hi(u1.y), a3v);
        a4 = fmaf(w1, bf_lo(u1.z), a4); a5 = fmaf(w1, bf_hi(u1.z), a5);
        a6 = fmaf(w1, bf_lo(u1.w), a6); a7 = fmaf(w1, bf_hi(u1.w), a7);
    }
    if (e < end) {
        int s = col[e];
        float qv = a1s[s * 4 + hsel];
        uint4 u = h1q[(size_t)s * 16 + c];
        float w = __expf(lrelu(qv + advh));
        den += w;
        a0 = fmaf(w, bf_lo(u.x), a0); a1v = fmaf(w, bf_hi(u.x), a1v);
        a2v = fmaf(w, bf_lo(u.y), a2v); a3v = fmaf(w, bf_hi(u.y), a3v);
        a4 = fmaf(w, bf_lo(u.z), a4); a5 = fmaf(w, bf_hi(u.z), a5);
        a6 = fmaf(w, bf_lo(u.w), a6); a7 = fmaf(w, bf_hi(u.w), a7);
    }
#define RED2(v) v += __shfl_xor(v, 16); v += __shfl_xor(v, 32);
    RED2(den) RED2(a0) RED2(a1v) RED2(a2v) RED2(a3v)
    RED2(a4) RED2(a5) RED2(a6) RED2(a7)
#undef RED2

    if (n0 < N && lane < 16) {
        float inv = 1.f / den;
        float v0 = a0 * inv + gb1[8 * c + 0];
        float v1 = a1v * inv + gb1[8 * c + 1];
        float v2 = a2v * inv + gb1[8 * c + 2];
        float v3 = a3v * inv + gb1[8 * c + 3];
        float v4 = a4 * inv + gb1[8 * c + 4];
        float v5 = a5 * inv + gb1[8 * c + 5];
        float v6 = a6 * inv + gb1[8 * c + 6];
        float v7 = a7 * inv + gb1[8 * c + 7];
        v0 = (v0 > 0.f) ? v0 : (__expf(v0) - 1.f);
        v1 = (v1 > 0.f) ? v1 : (__expf(v1) - 1.f);
        v2 = (v2 > 0.f) ? v2 : (__expf(v2) - 1.f);
        v3 = (v3 > 0.f) ? v3 : (__expf(v3) - 1.f);
        v4 = (v4 > 0.f) ? v4 : (__expf(v4) - 1.f);
        v5 = (v5 > 0.f) ? v5 : (__expf(v5) - 1.f);
        v6 = (v6 > 0.f) ? v6 : (__expf(v6) - 1.f);
        v7 = (v7 > 0.f) ? v7 : (__expf(v7) - 1.f);
        uint4 o;
        o.x = pack_bf16(v0, v1); o.y = pack_bf16(v2, v3);
        o.z = pack_bf16(v4, v5); o.w = pack_bf16(v6, v7);
        *reinterpret_cast<uint4*>(out1u + (size_t)n * 64 + 4 * c) = o;
    }
}

// ---------------------------------------------------------------------------
// GATConv2 projection via MFMA: h2 = out1 @ gW2 (bf16 in/out) + scores.
// ---------------------------------------------------------------------------
__global__ __launch_bounds__(256) void k_g2a(const unsigned short* __restrict__ out1b,
                                             const float* __restrict__ gW2,
                                             const float* __restrict__ a2sw,
                                             const float* __restrict__ a2dw,
                                             unsigned short* __restrict__ h2b,
                                             float* __restrict__ a2s,
                                             float* __restrict__ a2d, int N) {
    int lane = threadIdx.x & 63;
    int wid  = (blockIdx.x * blockDim.x + threadIdx.x) >> 6;
    int nwav = (gridDim.x * blockDim.x) >> 6;
    int col = lane & 15, g4 = lane >> 4;

    short8v Bf[4][4];
#pragma unroll
    for (int ks = 0; ks < 4; ++ks)
#pragma unroll
        for (int cb = 0; cb < 4; ++cb) {
            union { short8v v; unsigned short u[8]; } bu;
#pragma unroll
            for (int j = 0; j < 8; ++j)
                bu.u[j] = f2bf_rne(gW2[(ks * 32 + g4 * 8 + j) * 64 + cb * 16 + col]);
            Bf[ks][cb] = bu.v;
        }
    float asv[4], adv[4];
#pragma unroll
    for (int cb = 0; cb < 4; ++cb) { asv[cb] = a2sw[cb * 16 + col]; adv[cb] = a2dw[cb * 16 + col]; }

    int ntile = (N + 15) >> 4;
    for (int t = wid; t < ntile; t += nwav) {
        int n0 = t * 16;
        int node = n0 + col; if (node >= N) node = N - 1;
        const unsigned short* xr = out1b + (size_t)node * 128;
        f32x4 acc0 = {0.f, 0.f, 0.f, 0.f}, acc1 = acc0, acc2 = acc0, acc3 = acc0;
#pragma unroll
        for (int ks = 0; ks < 4; ++ks) {
            short8v a = *reinterpret_cast<const short8v*>(xr + ks * 32 + g4 * 8);
            acc0 = __builtin_amdgcn_mfma_f32_16x16x32_bf16(a, Bf[ks][0], acc0, 0, 0, 0);
            acc1 = __builtin_amdgcn_mfma_f32_16x16x32_bf16(a, Bf[ks][1], acc1, 0, 0, 0);
            acc2 = __builtin_amdgcn_mfma_f32_16x16x32_bf16(a, Bf[ks][2], acc2, 0, 0, 0);
            acc3 = __builtin_amdgcn_mfma_f32_16x16x32_bf16(a, Bf[ks][3], acc3, 0, 0, 0);
        }
        float ps[4] = {0.f, 0.f, 0.f, 0.f}, pd[4] = {0.f, 0.f, 0.f, 0.f};
#define G2A_EPI(CB, ACC)                                                      \
        {                                                                     \
            _Pragma("unroll")                                                 \
            for (int i = 0; i < 4; ++i) {                                     \
                float v = ACC[i];                                             \
                int r = n0 + g4 * 4 + i;                                      \
                if (r < N) h2b[(size_t)r * 64 + CB * 16 + col] = f2bf_rne(v); \
                ps[i] = fmaf(v, asv[CB], ps[i]);                              \
                pd[i] = fmaf(v, adv[CB], pd[i]);                              \
            }                                                                 \
        }
        G2A_EPI(0, acc0) G2A_EPI(1, acc1) G2A_EPI(2, acc2) G2A_EPI(3, acc3)
#undef G2A_EPI
#pragma unroll
        for (int i = 0; i < 4; ++i) {
            ps[i] += __shfl_xor(ps[i], 1); ps[i] += __shfl_xor(ps[i], 2);
            ps[i] += __shfl_xor(ps[i], 4); ps[i] += __shfl_xor(ps[i], 8);
            pd[i] += __shfl_xor(pd[i], 1); pd[i] += __shfl_xor(pd[i], 2);
            pd[i] += __shfl_xor(pd[i], 4); pd[i] += __shfl_xor(pd[i], 8);
        }
        if (col == 0) {
#pragma unroll
            for (int i = 0; i < 4; ++i) {
                int r = n0 + g4 * 4 + i;
                if (r < N) { a2s[r] = ps[i]; a2d[r] = pd[i]; }
            }
        }
    }
}

// ---------------------------------------------------------------------------
// GATConv2 aggregation. Eighth-wave per edge stream; index-ahead pipelining.
// ---------------------------------------------------------------------------
__global__ __launch_bounds__(256) void k_g2b(const int* __restrict__ rowptr,
                                             const int* __restrict__ col,
                                             const unsigned int* __restrict__ h2u,
                                             const float* __restrict__ a2s,
                                             const float* __restrict__ a2d,
                                             const float* __restrict__ gb2,
                                             unsigned int* __restrict__ gu, int N) {
    int tid = threadIdx.x, lane = tid & 63;
    int n0 = blockIdx.x * 4 + (tid >> 6);
    int n  = __builtin_amdgcn_readfirstlane(n0 < N ? n0 : N - 1);

    int start = rowptr[n], end = rowptr[n + 1];
    int q = lane >> 3, c = lane & 7;     // stream q; channels 8c..8c+7
    float ad = a2d[n];
    const uint4* h2q = reinterpret_cast<const uint4*>(h2u);

    float den = 0.f;
    float a0 = 0.f, a1v = 0.f, a2v = 0.f, a3v = 0.f;
    float a4 = 0.f, a5 = 0.f, a6 = 0.f, a7 = 0.f;
    if (q == 0) {                        // self loop on stream 0
        float w = __expf(lrelu(a2s[n] + ad));
        uint4 u = h2q[(size_t)n * 8 + c];
        den = w;
        a0 = w * bf_lo(u.x); a1v = w * bf_hi(u.x);
        a2v = w * bf_lo(u.y); a3v = w * bf_hi(u.y);
        a4 = w * bf_lo(u.z); a5 = w * bf_hi(u.z);
        a6 = w * bf_lo(u.w); a7 = w * bf_hi(u.w);
    }
    int e = start + q;
    int s = (e < end) ? col[e] : 0;
    for (; e < end; ) {
        int cs = s;
        e += 8;
        if (e < end) s = col[e];          // index-ahead
        float w = __expf(lrelu(a2s[cs] + ad));
        uint4 u = h2q[(size_t)cs * 8 + c];
        den += w;
        a0 = fmaf(w, bf_lo(u.x), a0); a1v = fmaf(w, bf_hi(u.x), a1v);
        a2v = fmaf(w, bf_lo(u.y), a2v); a3v = fmaf(w, bf_hi(u.y), a3v);
        a4 = fmaf(w, bf_lo(u.z), a4); a5 = fmaf(w, bf_hi(u.z), a5);
        a6 = fmaf(w, bf_lo(u.w), a6); a7 = fmaf(w, bf_hi(u.w), a7);
    }
#define RED3(v) v += __shfl_xor(v, 8); v += __shfl_xor(v, 16); v += __shfl_xor(v, 32);
    RED3(den) RED3(a0) RED3(a1v) RED3(a2v) RED3(a3v)
    RED3(a4) RED3(a5) RED3(a6) RED3(a7)
#undef RED3

    if (n0 < N && lane < 8) {
        float inv = 1.f / den;
        uint4 o;
        o.x = pack_bf16(a0 * inv + gb2[8 * c + 0], a1v * inv + gb2[8 * c + 1]);
        o.y = pack_bf16(a2v * inv + gb2[8 * c + 2], a3v * inv + gb2[8 * c + 3]);
        o.z = pack_bf16(a4 * inv + gb2[8 * c + 4], a5 * inv + gb2[8 * c + 5]);
        o.w = pack_bf16(a6 * inv + gb2[8 * c + 6], a7 * inv + gb2[8 * c + 7]);
        *reinterpret_cast<uint4*>(gu + (size_t)n * 32 + 4 * c) = o;
    }
}

// ---------------------------------------------------------------------------
// Classifier via MFMA: sigmoid(relu([m,g] @ Wf + bc) @ cW2 + cb2)
// ---------------------------------------------------------------------------
__global__ __launch_bounds__(256) void k_cls(const unsigned short* __restrict__ mb,
                                             const unsigned short* __restrict__ gb,
                                             const unsigned short* __restrict__ Wf,
                                             const float* __restrict__ bc,
                                             const float* __restrict__ cW2,
                                             const float* __restrict__ cb2,
                                             float* __restrict__ out, int N) {
    int lane = threadIdx.x & 63;
    int wid  = (blockIdx.x * blockDim.x + threadIdx.x) >> 6;
    int nwav = (gridDim.x * blockDim.x) >> 6;
    int col = lane & 15, g4 = lane >> 4;

    short8v Bf[4][4];
#pragma unroll
    for (int ks = 0; ks < 4; ++ks)
#pragma unroll
        for (int cb = 0; cb < 4; ++cb) {
            union { short8v v; unsigned short u[8]; } bu;
#pragma unroll
            for (int j = 0; j < 8; ++j)
                bu.u[j] = Wf[(ks * 32 + g4 * 8 + j) * 64 + cb * 16 + col];
            Bf[ks][cb] = bu.v;
        }
    float w2v[4], bcv[4];
#pragma unroll
    for (int cb = 0; cb < 4; ++cb) { w2v[cb] = cW2[cb * 16 + col]; bcv[cb] = bc[cb * 16 + col]; }
    float cb2v = cb2[0];

    int ntile = (N + 15) >> 4;
    for (int t = wid; t < ntile; t += nwav) {
        int n0 = t * 16;
        int node = n0 + col; if (node >= N) node = N - 1;
        const unsigned short* mr = mb + (size_t)node * 64;
        const unsigned short* gr = gb + (size_t)node * 64;
        f32x4 acc0 = {0.f, 0.f, 0.f, 0.f}, acc1 = acc0, acc2 = acc0, acc3 = acc0;
#pragma unroll
        for (int ks = 0; ks < 4; ++ks) {
            short8v a = (ks < 2)
                ? *reinterpret_cast<const short8v*>(mr + ks * 32 + g4 * 8)
                : *reinterpret_cast<const short8v*>(gr + (ks - 2) * 32 + g4 * 8);
            acc0 = __builtin_amdgcn_mfma_f32_16x16x32_bf16(a, Bf[ks][0], acc0, 0, 0, 0);
            acc1 = __builtin_amdgcn_mfma_f32_16x16x32_bf16(a, Bf[ks][1], acc1, 0, 0, 0);
            acc2 = __builtin_amdgcn_mfma_f32_16x16x32_bf16(a, Bf[ks][2], acc2, 0, 0, 0);
            acc3 = __builtin_amdgcn_mfma_f32_16x16x32_bf16(a, Bf[ks][3], acc3, 0, 0, 0);
        }
        float z[4] = {0.f, 0.f, 0.f, 0.f};
#define CLS_EPI(CB, ACC)                                                   \
        {                                                                  \
            _Pragma("unroll")                                              \
            for (int i = 0; i < 4; ++i)                                    \
                z[i] = fmaf(fmaxf(ACC[i] + bcv[CB], 0.f), w2v[CB], z[i]);  \
        }
        CLS_EPI(0, acc0) CLS_EPI(1, acc1) CLS_EPI(2, acc2) CLS_EPI(3, acc3)
#undef CLS_EPI
#pragma unroll
        for (int i = 0; i < 4; ++i) {
            z[i] += __shfl_xor(z[i], 1); z[i] += __shfl_xor(z[i], 2);
            z[i] += __shfl_xor(z[i], 4); z[i] += __shfl_xor(z[i], 8);
        }
        if (col == 0) {
#pragma unroll
            for (int i = 0; i < 4; ++i) {
                int r = n0 + g4 * 4 + i;
                if (r < N) out[r] = 1.f / (1.f + __expf(-(z[i] + cb2v)));
            }
        }
    }
}

// ---------------------------------------------------------------------------
extern "C" void kernel_launch(void* const* d_in, const int* in_sizes, int n_in,
                              void* d_out, int out_size, void* d_ws, size_t ws_size,
                              hipStream_t stream) {
    const float* td   = (const float*)d_in[0];
    const float* x    = (const float*)d_in[1];
    const int*   ei   = (const int*)d_in[2];
    const float* tW1  = (const float*)d_in[3];
    const float* tb1  = (const float*)d_in[4];
    const float* tW2  = (const float*)d_in[5];
    const float* tb2  = (const float*)d_in[6];
    const float* gW1  = (const float*)d_in[7];
    const float* ga1s = (const float*)d_in[8];
    const float* ga1d = (const float*)d_in[9];
    const float* gb1  = (const float*)d_in[10];
    const float* gW2  = (const float*)d_in[11];
    const float* ga2s = (const float*)d_in[12];
    const float* ga2d = (const float*)d_in[13];
    const float* gb2  = (const float*)d_in[14];
    const float* cW1  = (const float*)d_in[15];
    const float* cb1  = (const float*)d_in[16];
    const float* cW2  = (const float*)d_in[17];
    const float* cb2  = (const float*)d_in[18];

    int N = in_sizes[1] / 10;
    int E = in_sizes[2] / 2;

    float* fws = (float*)d_ws;
    unsigned short* mb16   = (unsigned short*)fws;                    // [N,64] bf16
    unsigned short* h1b    = (unsigned short*)(fws + (size_t)N * 32); // [N,128] bf16
    unsigned short* out1b  = (unsigned short*)(fws + (size_t)N * 96); // [N,128] bf16
    float* a1s   = fws + (size_t)N * 160;
    float* a1d   = fws + (size_t)N * 164;
    unsigned short* h2b = h1b;       // reuse (h1 dead after k_g1b)  [N,64] bf16
    float* a2s   = a1s;              // reuse
    float* a2d   = a1d;              // reuse
    unsigned short* gb16 = out1b;    // reuse (out1 dead after k_g2a) [N,64] bf16

    int* ib       = (int*)(fws + (size_t)N * 168);
    int* counts   = ib;
    int* rowptr   = ib + N;
    int* nxt      = ib + 2 * N + 1;
    int* partials = ib + 3 * N + 1;
    int* col      = ib + 3 * N + 1 + 128;

    unsigned short* Wf = (unsigned short*)(col + E);
    float* bcf = (float*)(Wf + 8192);

    int NB = (N + 1023) / 1024;
    int range = (N + SC_P - 1) / SC_P;
    int nb4   = (N + 3) / 4;
    int ntile = (N + 15) / 16;
    int nbt   = (ntile + 3) / 4;

    k_zero<<<256, 256, 0, stream>>>(counts, N);

    k_temporal<<<4096, 256, 0, stream>>>(td, tW1, tb1, ei, counts,
                                         tW2, cW1, tb2, cb1, Wf, bcf, mb16, N, E);
    k_scan1  <<<NB, 1024, 0, stream>>>(counts, rowptr, partials, N);
    k_scan3  <<<(N + 1 + 255) / 256, 256, 0, stream>>>(rowptr, partials, nxt, N);
    k_scatter<<<(E + 256 * SC_K - 1) / (256 * SC_K), 256, 0, stream>>>(ei, nxt, col, E, range);

    k_g1a<<<nb4, 256, 0, stream>>>(x, gW1, ga1s, ga1d, h1b, a1s, a1d, N);
    k_g1b<<<nb4, 256, 0, stream>>>(rowptr, col, (const unsigned int*)h1b, a1s, a1d, gb1,
                                   (unsigned int*)out1b, N);
    k_g2a<<<nbt, 256, 0, stream>>>(out1b, gW2, ga2s, ga2d, h2b, a2s, a2d, N);
    k_g2b<<<nb4, 256, 0, stream>>>(rowptr, col, (const unsigned int*)h2b, a2s, a2d, gb2,
                                   (unsigned int*)gb16, N);
    k_cls<<<nbt, 256, 0, stream>>>(mb16, gb16, Wf, bcf, cW2, cb2, (float*)d_out, N);
}

// Round 19
// 366.265 us; speedup vs baseline: 1.1383x; 1.0185x over previous
//
#include <hip/hip_runtime.h>
#include <hip/hip_bf16.h>

#define DEV_INLINE __device__ __forceinline__

typedef __attribute__((ext_vector_type(8))) short short8v;
typedef __attribute__((ext_vector_type(4))) float f32x4;

DEV_INLINE float lrelu(float v) { return fmaxf(v, 0.2f * v); }

DEV_INLINE unsigned int cvt_pk_bf16(float lo, float hi) {
    unsigned int r;
    asm("v_cvt_pk_bf16_f32 %0, %1, %2" : "=v"(r) : "v"(lo), "v"(hi));
    return r;
}

DEV_INLINE unsigned short f2bf_rne(float f) {
    unsigned int b = __float_as_uint(f);
    return (unsigned short)((b + 0x7FFFu + ((b >> 16) & 1u)) >> 16);
}

DEV_INLINE unsigned int pack_bf16(float lo, float hi) {
    return (unsigned int)f2bf_rne(lo) | ((unsigned int)f2bf_rne(hi) << 16);
}

DEV_INLINE float bf_lo(unsigned int u) { return __uint_as_float(u << 16); }
DEV_INLINE float bf_hi(unsigned int u) { return __uint_as_float(u & 0xFFFF0000u); }

// ---------------------------------------------------------------------------
__global__ void k_zero(int* __restrict__ p, int n) {
    int i = blockIdx.x * blockDim.x + threadIdx.x;
    int stride = gridDim.x * blockDim.x;
    for (; i < n; i += stride) p[i] = 0;
}

// ---------------------------------------------------------------------------
// CSR scan kernels
// ---------------------------------------------------------------------------
__global__ __launch_bounds__(1024) void k_scan1(const int* __restrict__ counts,
                                                int* __restrict__ rowptr,
                                                int* __restrict__ partials, int N) {
    __shared__ int sd[1024];
    int li = threadIdx.x;
    int i  = blockIdx.x * 1024 + li;
    int v  = (i < N) ? counts[i] : 0;
    sd[li] = v;
    __syncthreads();
    for (int off = 1; off < 1024; off <<= 1) {
        int t = (li >= off) ? sd[li - off] : 0;
        __syncthreads();
        sd[li] += t;
        __syncthreads();
    }
    int inc = sd[li];
    if (i < N) rowptr[i + 1] = inc;
    if (li == 1023) partials[blockIdx.x] = inc;   // raw chunk totals
}

__global__ void k_scan3(int* __restrict__ rowptr, const int* __restrict__ partials,
                        int* __restrict__ nxt, int N) {
    int i = blockIdx.x * blockDim.x + threadIdx.x;
    if (i > N) return;
    int v;
    if (i == 0) { v = 0; rowptr[0] = 0; }
    else {
        int blk = (i - 1) >> 10;
        int pp = 0;
        for (int b = 0; b < blk; ++b) pp += partials[b];
        v = rowptr[i] + pp;
        rowptr[i] = v;
    }
    if (i < N) nxt[i] = v;
}

#define SC_K 8
#define SC_P 16
__global__ __launch_bounds__(256) void k_scatter(const int* __restrict__ ei,
                                                 int* __restrict__ nxt,
                                                 int* __restrict__ col,
                                                 int E, int range) {
    int t = threadIdx.x;
    int base = blockIdx.x * (256 * SC_K);
    int s[SC_K], d[SC_K];
#pragma unroll
    for (int k = 0; k < SC_K; ++k) {
        int e = base + k * 256 + t;
        bool v = (e < E);
        s[k] = v ? ei[e] : 0;
        d[k] = v ? ei[E + e] : -1;
    }
    int lo = 0;
    for (int p = 0; p < SC_P; ++p, lo += range) {
        int hi = lo + range;
#pragma unroll
        for (int k = 0; k < SC_K; ++k) {
            if (d[k] >= lo && d[k] < hi) {
                int pos = atomicAdd(&nxt[d[k]], 1);
                col[pos] = s[k];
            }
        }
        __syncthreads();
    }
}

// ---------------------------------------------------------------------------
// Per-node temporal compute from an LDS slot (512 floats). 3 MFMA tiles cover
// t=0..47; t=48,49 as fp32 VALU tail with lane=channel weights.
// ---------------------------------------------------------------------------
DEV_INLINE void temporal_node(const float* wb, int col, int g, const short8v* B,
                              const float* w1c, float b1c,
                              int lane, unsigned short* mb, size_t n) {
    float sum0 = 0.f, sum1 = 0.f, sum2 = 0.f, sum3 = 0.f;
#pragma unroll
    for (int tt = 0; tt < 3; ++tt) {
        int t = tt * 16 + col;
        float x0 = 0.f, x1 = 0.f, x2 = 0.f, x3 = 0.f;
        float x4 = 0.f, x5 = 0.f, x6 = 0.f, x7 = 0.f;
        const float* rp = wb + t * 10;
        if (g == 0) {
            float2 p0 = *reinterpret_cast<const float2*>(rp);
            float2 p1 = *reinterpret_cast<const float2*>(rp + 2);
            float2 p2 = *reinterpret_cast<const float2*>(rp + 4);
            float2 p3 = *reinterpret_cast<const float2*>(rp + 6);
            x0 = p0.x; x1 = p0.y; x2 = p1.x; x3 = p1.y;
            x4 = p2.x; x5 = p2.y; x6 = p3.x; x7 = p3.y;
        } else if (g == 1) {
            float2 p4 = *reinterpret_cast<const float2*>(rp + 8);
            x0 = p4.x; x1 = p4.y; x2 = 1.0f;
        }
        union { short8v v; unsigned int w[4]; } au;
        au.w[0] = cvt_pk_bf16(x0, x1);
        au.w[1] = cvt_pk_bf16(x2, x3);
        au.w[2] = cvt_pk_bf16(x4, x5);
        au.w[3] = cvt_pk_bf16(x6, x7);

        f32x4 z = {0.f, 0.f, 0.f, 0.f};
        f32x4 c0 = __builtin_amdgcn_mfma_f32_16x16x32_bf16(au.v, B[0], z, 0, 0, 0);
        f32x4 c1 = __builtin_amdgcn_mfma_f32_16x16x32_bf16(au.v, B[1], z, 0, 0, 0);
        f32x4 c2 = __builtin_amdgcn_mfma_f32_16x16x32_bf16(au.v, B[2], z, 0, 0, 0);
        f32x4 c3 = __builtin_amdgcn_mfma_f32_16x16x32_bf16(au.v, B[3], z, 0, 0, 0);
#pragma unroll
        for (int i = 0; i < 4; ++i) {
            sum0 += fmaxf(c0[i], 0.f);
            sum1 += fmaxf(c1[i], 0.f);
            sum2 += fmaxf(c2[i], 0.f);
            sum3 += fmaxf(c3[i], 0.f);
        }
    }
    sum0 += __shfl_xor(sum0, 16); sum0 += __shfl_xor(sum0, 32);
    sum1 += __shfl_xor(sum1, 16); sum1 += __shfl_xor(sum1, 32);
    sum2 += __shfl_xor(sum2, 16); sum2 += __shfl_xor(sum2, 32);
    sum3 += __shfl_xor(sum3, 16); sum3 += __shfl_xor(sum3, 32);
    float mv = (g == 0) ? sum0 : (g == 1) ? sum1 : (g == 2) ? sum2 : sum3;

    const float* tp = wb + 480;
    float u48 = b1c, u49 = b1c;
#pragma unroll
    for (int i = 0; i < 10; ++i) {
        u48 = fmaf(tp[i],      w1c[i], u48);
        u49 = fmaf(tp[10 + i], w1c[i], u49);
    }
    mv += fmaxf(u48, 0.f) + fmaxf(u49, 0.f);

    mb[n * 64 + lane] = f2bf_rne(mv * 0.02f);
}

// ---------------------------------------------------------------------------
// Temporal encoder (+ folded edge-count histogram + classifier-weight fuse).
// Static double buffer, 2-node unrolled loop, distance-2 register staging.
// Grid 8192 (32768 waves, ~4 nodes/wave): chunk fully covered by prologue
// prefetch; maximal TLP for latency hiding.
// ---------------------------------------------------------------------------
__global__ __launch_bounds__(256) void k_temporal(const float* __restrict__ td,
                                                  const float* __restrict__ tW1,
                                                  const float* __restrict__ tb1,
                                                  const int* __restrict__ ei,
                                                  int* __restrict__ counts,
                                                  const float* __restrict__ tW2,
                                                  const float* __restrict__ cW1,
                                                  const float* __restrict__ tb2,
                                                  const float* __restrict__ cb1,
                                                  unsigned short* __restrict__ Wf,
                                                  float* __restrict__ bcf,
                                                  unsigned short* __restrict__ mb,
                                                  int N, int E) {
    __shared__ float b0lds[4][512];
    __shared__ float b1lds[4][512];
    int tid = threadIdx.x, lane = tid & 63, wv = tid >> 6;
    int gid = blockIdx.x * 256 + tid;

    // ---- folded k_count ----
    int estr = gridDim.x * 256;
    for (int e = gid; e < E; e += estr) atomicAdd(&counts[ei[E + e]], 1);

    // ---- folded k_fuse ----
    if (gid < 4096) {
        int i = gid >> 6, c = gid & 63;
        float s = 0.f;
#pragma unroll 8
        for (int k = 0; k < 64; ++k) s = fmaf(tW2[i * 64 + k], cW1[k * 64 + c], s);
        Wf[gid] = f2bf_rne(s);
    } else if (gid < 8192) {
        Wf[gid] = f2bf_rne(cW1[gid]);
    } else if (gid < 8256) {
        int c = gid - 8192;
        float s = cb1[c];
#pragma unroll 8
        for (int k = 0; k < 64; ++k) s = fmaf(tb2[k], cW1[k * 64 + c], s);
        bcf[c] = s;
    }

    int wid  = gid >> 6;
    int nwav = (gridDim.x * 256) >> 6;
    int col  = lane & 15;
    int g    = lane >> 4;

    int chunk = (N + nwav - 1) / nwav;
    int n0 = wid * chunk;
    int n1 = min(n0 + chunk, N);
    if (n0 >= n1) return;
    int cnt = n1 - n0;

    short8v B[4];
#pragma unroll
    for (int cb = 0; cb < 4; ++cb) {
        union { short8v v; unsigned short u[8]; } bu;
#pragma unroll
        for (int j = 0; j < 8; ++j) {
            int f = g * 8 + j;
            int c = cb * 16 + col;
            float w = (f < 10) ? tW1[f * 64 + c] : ((f == 10) ? tb1[c] : 0.f);
            bu.u[j] = f2bf_rne(w);
        }
        B[cb] = bu.v;
    }
    float w1c[10];
#pragma unroll
    for (int i = 0; i < 10; ++i) w1c[i] = tW1[i * 64 + lane];
    float b1c = tb1[lane];

    float* buf0 = &b0lds[wv][0];
    float* buf1 = &b1lds[wv][0];
    float4 zero4 = make_float4(0.f, 0.f, 0.f, 0.f);

#define LOADROW(J, A, Bv)                                                      \
    {                                                                          \
        int nn = n0 + (J); if (nn > n1 - 1) nn = n1 - 1;                       \
        const float4* rr = reinterpret_cast<const float4*>(td + (size_t)nn * 500); \
        A = rr[lane];                                                          \
        Bv = (lane < 61) ? rr[64 + lane] : zero4;                              \
    }
#define WRITEBUF(BUF, A, Bv)                                                   \
    {                                                                          \
        *reinterpret_cast<float4*>((BUF) + 4 * lane) = A;                      \
        if (lane < 61) *reinterpret_cast<float4*>((BUF) + 256 + 4 * lane) = Bv;\
    }

    float4 aA, bA, aB, bB;
    LOADROW(0, aA, bA)
    LOADROW(1, aB, bB)
    WRITEBUF(buf0, aA, bA)
    LOADROW(2, aA, bA)
    WRITEBUF(buf1, aB, bB)
    LOADROW(3, aB, bB)

    int i = 0;
    for (; i + 1 < cnt; i += 2) {
        temporal_node(buf0, col, g, B, w1c, b1c, lane, mb, (size_t)(n0 + i));
        WRITEBUF(buf0, aA, bA)
        LOADROW(i + 4, aA, bA)
        temporal_node(buf1, col, g, B, w1c, b1c, lane, mb, (size_t)(n0 + i + 1));
        WRITEBUF(buf1, aB, bB)
        LOADROW(i + 5, aB, bB)
    }
    if (i < cnt)
        temporal_node(buf0, col, g, B, w1c, b1c, lane, mb, (size_t)(n0 + i));
#undef LOADROW
#undef WRITEBUF
}

// ---------------------------------------------------------------------------
// GATConv1 projection + attention scores. h1b bf16 [n,128], a1s/a1d fp32 [n,4]
// ---------------------------------------------------------------------------
__global__ __launch_bounds__(256) void k_g1a(const float* __restrict__ x,
                                             const float* __restrict__ gW1,
                                             const float* __restrict__ as_w,
                                             const float* __restrict__ ad_w,
                                             unsigned short* __restrict__ h1b,
                                             float* __restrict__ a1s,
                                             float* __restrict__ a1d, int N) {
    int tid = threadIdx.x, lane = tid & 63;
    int n0 = blockIdx.x * 4 + (tid >> 6);
    int n  = __builtin_amdgcn_readfirstlane(n0 < N ? n0 : N - 1);

    float wa[10], wb[10];
#pragma unroll
    for (int i = 0; i < 10; ++i) { wa[i] = gW1[i * 128 + lane]; wb[i] = gW1[i * 128 + 64 + lane]; }
    const float* xp = x + (size_t)n * 10;
    float ha = 0.f, hb = 0.f;
#pragma unroll
    for (int i = 0; i < 10; ++i) { float xv = xp[i]; ha = fmaf(xv, wa[i], ha); hb = fmaf(xv, wb[i], hb); }

    int c = lane & 31;
    int headA = lane >> 5;
    float ps_a = ha * as_w[headA * 32 + c];
    float ps_b = hb * as_w[(headA + 2) * 32 + c];
    float pd_a = ha * ad_w[headA * 32 + c];
    float pd_b = hb * ad_w[(headA + 2) * 32 + c];
#pragma unroll
    for (int m = 1; m < 32; m <<= 1) {
        ps_a += __shfl_xor(ps_a, m); ps_b += __shfl_xor(ps_b, m);
        pd_a += __shfl_xor(pd_a, m); pd_b += __shfl_xor(pd_b, m);
    }
    if (n0 < N) {
        h1b[(size_t)n * 128 + lane]      = f2bf_rne(ha);
        h1b[(size_t)n * 128 + 64 + lane] = f2bf_rne(hb);
        if (c == 0) {
            a1s[n * 4 + headA]     = ps_a;
            a1s[n * 4 + 2 + headA] = ps_b;
            a1d[n * 4 + headA]     = pd_a;
            a1d[n * 4 + 2 + headA] = pd_b;
        }
    }
}

// ---------------------------------------------------------------------------
// GATConv1 aggregation. Quarter-wave per edge stream; index-ahead pipelining.
// ---------------------------------------------------------------------------
__global__ __launch_bounds__(256) void k_g1b(const int* __restrict__ rowptr,
                                             const int* __restrict__ col,
                                             const unsigned int* __restrict__ h1u,
                                             const float* __restrict__ a1s,
                                             const float* __restrict__ a1d,
                                             const float* __restrict__ gb1,
                                             unsigned int* __restrict__ out1u, int N) {
    int tid = threadIdx.x, lane = tid & 63;
    int n0 = blockIdx.x * 4 + (tid >> 6);
    int n  = __builtin_amdgcn_readfirstlane(n0 < N ? n0 : N - 1);

    int start = rowptr[n], end = rowptr[n + 1];
    int q = lane >> 4, c = lane & 15;     // stream q; channels 8c..8c+7
    int hsel = c >> 2;                    // head
    float advh = a1d[n * 4 + hsel];
    const uint4* h1q = reinterpret_cast<const uint4*>(h1u);

    float den = 0.f;
    float a0 = 0.f, a1v = 0.f, a2v = 0.f, a3v = 0.f;
    float a4 = 0.f, a5 = 0.f, a6 = 0.f, a7 = 0.f;
    if (q == 0) {                         // self loop on stream 0
        float w = __expf(lrelu(a1s[n * 4 + hsel] + advh));
        uint4 u = h1q[(size_t)n * 16 + c];
        den = w;
        a0 = w * bf_lo(u.x); a1v = w * bf_hi(u.x);
        a2v = w * bf_lo(u.y); a3v = w * bf_hi(u.y);
        a4 = w * bf_lo(u.z); a5 = w * bf_hi(u.z);
        a6 = w * bf_lo(u.w); a7 = w * bf_hi(u.w);
    }
    int e = start + q;
    int s0 = 0, s1 = 0;
    bool have2 = (e + 4 < end);
    if (have2) { s0 = col[e]; s1 = col[e + 4]; }
    for (; e + 4 < end; ) {
        int cs0 = s0, cs1 = s1;
        e += 8;
        if (e + 4 < end) { s0 = col[e]; s1 = col[e + 4]; }   // index-ahead
        float q0 = a1s[cs0 * 4 + hsel];
        float q1 = a1s[cs1 * 4 + hsel];
        uint4 u0 = h1q[(size_t)cs0 * 16 + c];
        uint4 u1 = h1q[(size_t)cs1 * 16 + c];
        float w0 = __expf(lrelu(q0 + advh));
        float w1 = __expf(lrelu(q1 + advh));
        den += w0 + w1;
        a0 = fmaf(w0, bf_lo(u0.x), a0); a1v = fmaf(w0, bf_hi(u0.x), a1v);
        a2v = fmaf(w0, bf_lo(u0.y), a2v); a3v = fmaf(w0, bf_hi(u0.y), a3v);
        a4 = fmaf(w0, bf_lo(u0.z), a4); a5 = fmaf(w0, bf_hi(u0.z), a5);
        a6 = fmaf(w0, bf_lo(u0.w), a6); a7 = fmaf(w0, bf_hi(u0.w), a7);
        a0 = fmaf(w1, bf_lo(u1.x), a0); a1v = fmaf(w1, bf_hi(u1.x), a1v);
        a2v = fmaf(w1, bf_lo(u1.y), a2v); a3v = fmaf(w1, bf_hi(u1.y), a3v);
        a4 = fmaf(w1, bf_lo(u1.z), a4); a5 = fmaf(w1, bf_hi(u1.z), a5);
        a6 = fmaf(w1, bf_lo(u1.w), a6); a7 = fmaf(w1, bf_hi(u1.w), a7);
    }
    if (e < end) {
        int s = col[e];
        float qv = a1s[s * 4 + hsel];
        uint4 u = h1q[(size_t)s * 16 + c];
        float w = __expf(lrelu(qv + advh));
        den += w;
        a0 = fmaf(w, bf_lo(u.x), a0); a1v = fmaf(w, bf_hi(u.x), a1v);
        a2v = fmaf(w, bf_lo(u.y), a2v); a3v = fmaf(w, bf_hi(u.y), a3v);
        a4 = fmaf(w, bf_lo(u.z), a4); a5 = fmaf(w, bf_hi(u.z), a5);
        a6 = fmaf(w, bf_lo(u.w), a6); a7 = fmaf(w, bf_hi(u.w), a7);
    }
#define RED2(v) v += __shfl_xor(v, 16); v += __shfl_xor(v, 32);
    RED2(den) RED2(a0) RED2(a1v) RED2(a2v) RED2(a3v)
    RED2(a4) RED2(a5) RED2(a6) RED2(a7)
#undef RED2

    if (n0 < N && lane < 16) {
        float inv = 1.f / den;
        float v0 = a0 * inv + gb1[8 * c + 0];
        float v1 = a1v * inv + gb1[8 * c + 1];
        float v2 = a2v * inv + gb1[8 * c + 2];
        float v3 = a3v * inv + gb1[8 * c + 3];
        float v4 = a4 * inv + gb1[8 * c + 4];
        float v5 = a5 * inv + gb1[8 * c + 5];
        float v6 = a6 * inv + gb1[8 * c + 6];
        float v7 = a7 * inv + gb1[8 * c + 7];
        v0 = (v0 > 0.f) ? v0 : (__expf(v0) - 1.f);
        v1 = (v1 > 0.f) ? v1 : (__expf(v1) - 1.f);
        v2 = (v2 > 0.f) ? v2 : (__expf(v2) - 1.f);
        v3 = (v3 > 0.f) ? v3 : (__expf(v3) - 1.f);
        v4 = (v4 > 0.f) ? v4 : (__expf(v4) - 1.f);
        v5 = (v5 > 0.f) ? v5 : (__expf(v5) - 1.f);
        v6 = (v6 > 0.f) ? v6 : (__expf(v6) - 1.f);
        v7 = (v7 > 0.f) ? v7 : (__expf(v7) - 1.f);
        uint4 o;
        o.x = pack_bf16(v0, v1); o.y = pack_bf16(v2, v3);
        o.z = pack_bf16(v4, v5); o.w = pack_bf16(v6, v7);
        *reinterpret_cast<uint4*>(out1u + (size_t)n * 64 + 4 * c) = o;
    }
}

// ---------------------------------------------------------------------------
// GATConv2 projection via MFMA: h2 = out1 @ gW2 (bf16 in/out) + scores.
// ---------------------------------------------------------------------------
__global__ __launch_bounds__(256) void k_g2a(const unsigned short* __restrict__ out1b,
                                             const float* __restrict__ gW2,
                                             const float* __restrict__ a2sw,
                                             const float* __restrict__ a2dw,
                                             unsigned short* __restrict__ h2b,
                                             float* __restrict__ a2s,
                                             float* __restrict__ a2d, int N) {
    int lane = threadIdx.x & 63;
    int wid  = (blockIdx.x * blockDim.x + threadIdx.x) >> 6;
    int nwav = (gridDim.x * blockDim.x) >> 6;
    int col = lane & 15, g4 = lane >> 4;

    short8v Bf[4][4];
#pragma unroll
    for (int ks = 0; ks < 4; ++ks)
#pragma unroll
        for (int cb = 0; cb < 4; ++cb) {
            union { short8v v; unsigned short u[8]; } bu;
#pragma unroll
            for (int j = 0; j < 8; ++j)
                bu.u[j] = f2bf_rne(gW2[(ks * 32 + g4 * 8 + j) * 64 + cb * 16 + col]);
            Bf[ks][cb] = bu.v;
        }
    float asv[4], adv[4];
#pragma unroll
    for (int cb = 0; cb < 4; ++cb) { asv[cb] = a2sw[cb * 16 + col]; adv[cb] = a2dw[cb * 16 + col]; }

    int ntile = (N + 15) >> 4;
    for (int t = wid; t < ntile; t += nwav) {
        int n0 = t * 16;
        int node = n0 + col; if (node >= N) node = N - 1;
        const unsigned short* xr = out1b + (size_t)node * 128;
        f32x4 acc0 = {0.f, 0.f, 0.f, 0.f}, acc1 = acc0, acc2 = acc0, acc3 = acc0;
#pragma unroll
        for (int ks = 0; ks < 4; ++ks) {
            short8v a = *reinterpret_cast<const short8v*>(xr + ks * 32 + g4 * 8);
            acc0 = __builtin_amdgcn_mfma_f32_16x16x32_bf16(a, Bf[ks][0], acc0, 0, 0, 0);
            acc1 = __builtin_amdgcn_mfma_f32_16x16x32_bf16(a, Bf[ks][1], acc1, 0, 0, 0);
            acc2 = __builtin_amdgcn_mfma_f32_16x16x32_bf16(a, Bf[ks][2], acc2, 0, 0, 0);
            acc3 = __builtin_amdgcn_mfma_f32_16x16x32_bf16(a, Bf[ks][3], acc3, 0, 0, 0);
        }
        float ps[4] = {0.f, 0.f, 0.f, 0.f}, pd[4] = {0.f, 0.f, 0.f, 0.f};
#define G2A_EPI(CB, ACC)                                                      \
        {                                                                     \
            _Pragma("unroll")                                                 \
            for (int i = 0; i < 4; ++i) {                                     \
                float v = ACC[i];                                             \
                int r = n0 + g4 * 4 + i;                                      \
                if (r < N) h2b[(size_t)r * 64 + CB * 16 + col] = f2bf_rne(v); \
                ps[i] = fmaf(v, asv[CB], ps[i]);                              \
                pd[i] = fmaf(v, adv[CB], pd[i]);                              \
            }                                                                 \
        }
        G2A_EPI(0, acc0) G2A_EPI(1, acc1) G2A_EPI(2, acc2) G2A_EPI(3, acc3)
#undef G2A_EPI
#pragma unroll
        for (int i = 0; i < 4; ++i) {
            ps[i] += __shfl_xor(ps[i], 1); ps[i] += __shfl_xor(ps[i], 2);
            ps[i] += __shfl_xor(ps[i], 4); ps[i] += __shfl_xor(ps[i], 8);
            pd[i] += __shfl_xor(pd[i], 1); pd[i] += __shfl_xor(pd[i], 2);
            pd[i] += __shfl_xor(pd[i], 4); pd[i] += __shfl_xor(pd[i], 8);
        }
        if (col == 0) {
#pragma unroll
            for (int i = 0; i < 4; ++i) {
                int r = n0 + g4 * 4 + i;
                if (r < N) { a2s[r] = ps[i]; a2d[r] = pd[i]; }
            }
        }
    }
}

// ---------------------------------------------------------------------------
// GATConv2 aggregation. Eighth-wave per edge stream; index-ahead pipelining.
// ---------------------------------------------------------------------------
__global__ __launch_bounds__(256) void k_g2b(const int* __restrict__ rowptr,
                                             const int* __restrict__ col,
                                             const unsigned int* __restrict__ h2u,
                                             const float* __restrict__ a2s,
                                             const float* __restrict__ a2d,
                                             const float* __restrict__ gb2,
                                             unsigned int* __restrict__ gu, int N) {
    int tid = threadIdx.x, lane = tid & 63;
    int n0 = blockIdx.x * 4 + (tid >> 6);
    int n  = __builtin_amdgcn_readfirstlane(n0 < N ? n0 : N - 1);

    int start = rowptr[n], end = rowptr[n + 1];
    int q = lane >> 3, c = lane & 7;     // stream q; channels 8c..8c+7
    float ad = a2d[n];
    const uint4* h2q = reinterpret_cast<const uint4*>(h2u);

    float den = 0.f;
    float a0 = 0.f, a1v = 0.f, a2v = 0.f, a3v = 0.f;
    float a4 = 0.f, a5 = 0.f, a6 = 0.f, a7 = 0.f;
    if (q == 0) {                        // self loop on stream 0
        float w = __expf(lrelu(a2s[n] + ad));
        uint4 u = h2q[(size_t)n * 8 + c];
        den = w;
        a0 = w * bf_lo(u.x); a1v = w * bf_hi(u.x);
        a2v = w * bf_lo(u.y); a3v = w * bf_hi(u.y);
        a4 = w * bf_lo(u.z); a5 = w * bf_hi(u.z);
        a6 = w * bf_lo(u.w); a7 = w * bf_hi(u.w);
    }
    int e = start + q;
    int s = (e < end) ? col[e] : 0;
    for (; e < end; ) {
        int cs = s;
        e += 8;
        if (e < end) s = col[e];          // index-ahead
        float w = __expf(lrelu(a2s[cs] + ad));
        uint4 u = h2q[(size_t)cs * 8 + c];
        den += w;
        a0 = fmaf(w, bf_lo(u.x), a0); a1v = fmaf(w, bf_hi(u.x), a1v);
        a2v = fmaf(w, bf_lo(u.y), a2v); a3v = fmaf(w, bf_hi(u.y), a3v);
        a4 = fmaf(w, bf_lo(u.z), a4); a5 = fmaf(w, bf_hi(u.z), a5);
        a6 = fmaf(w, bf_lo(u.w), a6); a7 = fmaf(w, bf_hi(u.w), a7);
    }
#define RED3(v) v += __shfl_xor(v, 8); v += __shfl_xor(v, 16); v += __shfl_xor(v, 32);
    RED3(den) RED3(a0) RED3(a1v) RED3(a2v) RED3(a3v)
    RED3(a4) RED3(a5) RED3(a6) RED3(a7)
#undef RED3

    if (n0 < N && lane < 8) {
        float inv = 1.f / den;
        uint4 o;
        o.x = pack_bf16(a0 * inv + gb2[8 * c + 0], a1v * inv + gb2[8 * c + 1]);
        o.y = pack_bf16(a2v * inv + gb2[8 * c + 2], a3v * inv + gb2[8 * c + 3]);
        o.z = pack_bf16(a4 * inv + gb2[8 * c + 4], a5 * inv + gb2[8 * c + 5]);
        o.w = pack_bf16(a6 * inv + gb2[8 * c + 6], a7 * inv + gb2[8 * c + 7]);
        *reinterpret_cast<uint4*>(gu + (size_t)n * 32 + 4 * c) = o;
    }
}

// ---------------------------------------------------------------------------
// Classifier via MFMA: sigmoid(relu([m,g] @ Wf + bc) @ cW2 + cb2)
// ---------------------------------------------------------------------------
__global__ __launch_bounds__(256) void k_cls(const unsigned short* __restrict__ mb,
                                             const unsigned short* __restrict__ gb,
                                             const unsigned short* __restrict__ Wf,
                                             const float* __restrict__ bc,
                                             const float* __restrict__ cW2,
                                             const float* __restrict__ cb2,
                                             float* __restrict__ out, int N) {
    int lane = threadIdx.x & 63;
    int wid  = (blockIdx.x * blockDim.x + threadIdx.x) >> 6;
    int nwav = (gridDim.x * blockDim.x) >> 6;
    int col = lane & 15, g4 = lane >> 4;

    short8v Bf[4][4];
#pragma unroll
    for (int ks = 0; ks < 4; ++ks)
#pragma unroll
        for (int cb = 0; cb < 4; ++cb) {
            union { short8v v; unsigned short u[8]; } bu;
#pragma unroll
            for (int j = 0; j < 8; ++j)
                bu.u[j] = Wf[(ks * 32 + g4 * 8 + j) * 64 + cb * 16 + col];
            Bf[ks][cb] = bu.v;
        }
    float w2v[4], bcv[4];
#pragma unroll
    for (int cb = 0; cb < 4; ++cb) { w2v[cb] = cW2[cb * 16 + col]; bcv[cb] = bc[cb * 16 + col]; }
    float cb2v = cb2[0];

    int ntile = (N + 15) >> 4;
    for (int t = wid; t < ntile; t += nwav) {
        int n0 = t * 16;
        int node = n0 + col; if (node >= N) node = N - 1;
        const unsigned short* mr = mb + (size_t)node * 64;
        const unsigned short* gr = gb + (size_t)node * 64;
        f32x4 acc0 = {0.f, 0.f, 0.f, 0.f}, acc1 = acc0, acc2 = acc0, acc3 = acc0;
#pragma unroll
        for (int ks = 0; ks < 4; ++ks) {
            short8v a = (ks < 2)
                ? *reinterpret_cast<const short8v*>(mr + ks * 32 + g4 * 8)
                : *reinterpret_cast<const short8v*>(gr + (ks - 2) * 32 + g4 * 8);
            acc0 = __builtin_amdgcn_mfma_f32_16x16x32_bf16(a, Bf[ks][0], acc0, 0, 0, 0);
            acc1 = __builtin_amdgcn_mfma_f32_16x16x32_bf16(a, Bf[ks][1], acc1, 0, 0, 0);
            acc2 = __builtin_amdgcn_mfma_f32_16x16x32_bf16(a, Bf[ks][2], acc2, 0, 0, 0);
            acc3 = __builtin_amdgcn_mfma_f32_16x16x32_bf16(a, Bf[ks][3], acc3, 0, 0, 0);
        }
        float z[4] = {0.f, 0.f, 0.f, 0.f};
#define CLS_EPI(CB, ACC)                                                   \
        {                                                                  \
            _Pragma("unroll")                                              \
            for (int i = 0; i < 4; ++i)                                    \
                z[i] = fmaf(fmaxf(ACC[i] + bcv[CB], 0.f), w2v[CB], z[i]);  \
        }
        CLS_EPI(0, acc0) CLS_EPI(1, acc1) CLS_EPI(2, acc2) CLS_EPI(3, acc3)
#undef CLS_EPI
#pragma unroll
        for (int i = 0; i < 4; ++i) {
            z[i] += __shfl_xor(z[i], 1); z[i] += __shfl_xor(z[i], 2);
            z[i] += __shfl_xor(z[i], 4); z[i] += __shfl_xor(z[i], 8);
        }
        if (col == 0) {
#pragma unroll
            for (int i = 0; i < 4; ++i) {
                int r = n0 + g4 * 4 + i;
                if (r < N) out[r] = 1.f / (1.f + __expf(-(z[i] + cb2v)));
            }
        }
    }
}

// ---------------------------------------------------------------------------
extern "C" void kernel_launch(void* const* d_in, const int* in_sizes, int n_in,
                              void* d_out, int out_size, void* d_ws, size_t ws_size,
                              hipStream_t stream) {
    const float* td   = (const float*)d_in[0];
    const float* x    = (const float*)d_in[1];
    const int*   ei   = (const int*)d_in[2];
    const float* tW1  = (const float*)d_in[3];
    const float* tb1  = (const float*)d_in[4];
    const float* tW2  = (const float*)d_in[5];
    const float* tb2  = (const float*)d_in[6];
    const float* gW1  = (const float*)d_in[7];
    const float* ga1s = (const float*)d_in[8];
    const float* ga1d = (const float*)d_in[9];
    const float* gb1  = (const float*)d_in[10];
    const float* gW2  = (const float*)d_in[11];
    const float* ga2s = (const float*)d_in[12];
    const float* ga2d = (const float*)d_in[13];
    const float* gb2  = (const float*)d_in[14];
    const float* cW1  = (const float*)d_in[15];
    const float* cb1  = (const float*)d_in[16];
    const float* cW2  = (const float*)d_in[17];
    const float* cb2  = (const float*)d_in[18];

    int N = in_sizes[1] / 10;
    int E = in_sizes[2] / 2;

    float* fws = (float*)d_ws;
    unsigned short* mb16   = (unsigned short*)fws;                    // [N,64] bf16
    unsigned short* h1b    = (unsigned short*)(fws + (size_t)N * 32); // [N,128] bf16
    unsigned short* out1b  = (unsigned short*)(fws + (size_t)N * 96); // [N,128] bf16
    float* a1s   = fws + (size_t)N * 160;
    float* a1d   = fws + (size_t)N * 164;
    unsigned short* h2b = h1b;       // reuse (h1 dead after k_g1b)  [N,64] bf16
    float* a2s   = a1s;              // reuse
    float* a2d   = a1d;              // reuse
    unsigned short* gb16 = out1b;    // reuse (out1 dead after k_g2a) [N,64] bf16

    int* ib       = (int*)(fws + (size_t)N * 168);
    int* counts   = ib;
    int* rowptr   = ib + N;
    int* nxt      = ib + 2 * N + 1;
    int* partials = ib + 3 * N + 1;
    int* col      = ib + 3 * N + 1 + 128;

    unsigned short* Wf = (unsigned short*)(col + E);
    float* bcf = (float*)(Wf + 8192);

    int NB = (N + 1023) / 1024;
    int range = (N + SC_P - 1) / SC_P;
    int nb4   = (N + 3) / 4;
    int ntile = (N + 15) / 16;
    int nbt   = (ntile + 3) / 4;

    k_zero<<<256, 256, 0, stream>>>(counts, N);

    k_temporal<<<8192, 256, 0, stream>>>(td, tW1, tb1, ei, counts,
                                         tW2, cW1, tb2, cb1, Wf, bcf, mb16, N, E);
    k_scan1  <<<NB, 1024, 0, stream>>>(counts, rowptr, partials, N);
    k_scan3  <<<(N + 1 + 255) / 256, 256, 0, stream>>>(rowptr, partials, nxt, N);
    k_scatter<<<(E + 256 * SC_K - 1) / (256 * SC_K), 256, 0, stream>>>(ei, nxt, col, E, range);

    k_g1a<<<nb4, 256, 0, stream>>>(x, gW1, ga1s, ga1d, h1b, a1s, a1d, N);
    k_g1b<<<nb4, 256, 0, stream>>>(rowptr, col, (const unsigned int*)h1b, a1s, a1d, gb1,
                                   (unsigned int*)out1b, N);
    k_g2a<<<nbt, 256, 0, stream>>>(out1b, gW2, ga2s, ga2d, h2b, a2s, a2d, N);
    k_g2b<<<nb4, 256, 0, stream>>>(rowptr, col, (const unsigned int*)h2b, a2s, a2d, gb2,
                                   (unsigned int*)gb16, N);
    k_cls<<<nbt, 256, 0, stream>>>(mb16, gb16, Wf, bcf, cW2, cb2, (float*)d_out, N);
}